// Round 1
// baseline (1268.613 us; speedup 1.0000x reference)
//
#include <hip/hip_runtime.h>
#include <cstddef>

#define NN   50000
#define EE   800000
#define TOTE 850000      // EE + NN self loops
#define INC  256
#define HEADS 8
#define HID  64
#define F1   512         // HEADS*HID
#define OUTC 64

// ---------------- GEMM: C[M,Nn] = A[M,K] @ B[K,Nn], f32, 64x64 tile ----------
__global__ __launch_bounds__(256)
void gemm64x64(const float* __restrict__ A, const float* __restrict__ B,
               float* __restrict__ C, int M, int K, int Nn) {
  __shared__ float As[64][17];
  __shared__ float Bs[16][68];
  const int tid = threadIdx.x;
  const int tx  = tid & 15;
  const int ty  = tid >> 4;
  const int rowBase = blockIdx.x * 64;
  const int colBase = blockIdx.y * 64;
  const int ar = tid >> 2, ac = (tid & 3) * 4;
  const int br = tid >> 4, bc = (tid & 15) * 4;
  float acc[4][4] = {};
  for (int kt = 0; kt < K; kt += 16) {
    float4 av = make_float4(0.f, 0.f, 0.f, 0.f);
    int grow = rowBase + ar;
    if (grow < M)
      av = *reinterpret_cast<const float4*>(A + (size_t)grow * K + kt + ac);
    As[ar][ac+0] = av.x; As[ar][ac+1] = av.y; As[ar][ac+2] = av.z; As[ar][ac+3] = av.w;
    float4 bv = *reinterpret_cast<const float4*>(B + (size_t)(kt + br) * Nn + colBase + bc);
    Bs[br][bc+0] = bv.x; Bs[br][bc+1] = bv.y; Bs[br][bc+2] = bv.z; Bs[br][bc+3] = bv.w;
    __syncthreads();
    #pragma unroll
    for (int k = 0; k < 16; ++k) {
      float a0 = As[ty][k], a1 = As[ty+16][k], a2 = As[ty+32][k], a3 = As[ty+48][k];
      float b0 = Bs[k][tx], b1 = Bs[k][tx+16], b2 = Bs[k][tx+32], b3 = Bs[k][tx+48];
      acc[0][0] += a0*b0; acc[0][1] += a0*b1; acc[0][2] += a0*b2; acc[0][3] += a0*b3;
      acc[1][0] += a1*b0; acc[1][1] += a1*b1; acc[1][2] += a1*b2; acc[1][3] += a1*b3;
      acc[2][0] += a2*b0; acc[2][1] += a2*b1; acc[2][2] += a2*b2; acc[2][3] += a2*b3;
      acc[3][0] += a3*b0; acc[3][1] += a3*b1; acc[3][2] += a3*b2; acc[3][3] += a3*b3;
    }
    __syncthreads();
  }
  #pragma unroll
  for (int i = 0; i < 4; ++i) {
    int r = rowBase + ty + 16 * i;
    if (r < M) {
      #pragma unroll
      for (int j = 0; j < 4; ++j)
        C[(size_t)r * Nn + colBase + tx + 16 * j] = acc[i][j];
    }
  }
}

// ---------------- alpha (layer 1): per node, 8 heads, wave reduce ------------
__global__ __launch_bounds__(256)
void alpha1_kernel(const float* __restrict__ H1, const float* __restrict__ a_src,
                   const float* __restrict__ a_dst,
                   float* __restrict__ AS, float* __restrict__ AD) {
  int wave = (blockIdx.x * blockDim.x + threadIdx.x) >> 6;
  int lane = threadIdx.x & 63;
  if (wave >= NN) return;
  const float* hp = H1 + (size_t)wave * F1;
  #pragma unroll
  for (int h = 0; h < HEADS; ++h) {
    float v = hp[h * 64 + lane];
    float s = v * a_src[h * 64 + lane];
    float d = v * a_dst[h * 64 + lane];
    #pragma unroll
    for (int off = 32; off > 0; off >>= 1) {
      s += __shfl_down(s, off);
      d += __shfl_down(d, off);
    }
    if (lane == 0) { AS[wave * HEADS + h] = s; AD[wave * HEADS + h] = d; }
  }
}

// ---------------- alpha (layer 2): per node, 1 head --------------------------
__global__ __launch_bounds__(256)
void alpha2_kernel(const float* __restrict__ H2, const float* __restrict__ a_src,
                   const float* __restrict__ a_dst,
                   float* __restrict__ AS, float* __restrict__ AD) {
  int wave = (blockIdx.x * blockDim.x + threadIdx.x) >> 6;
  int lane = threadIdx.x & 63;
  if (wave >= NN) return;
  float v = H2[(size_t)wave * OUTC + lane];
  float s = v * a_src[lane];
  float d = v * a_dst[lane];
  #pragma unroll
  for (int off = 32; off > 0; off >>= 1) {
    s += __shfl_down(s, off);
    d += __shfl_down(d, off);
  }
  if (lane == 0) { AS[wave] = s; AD[wave] = d; }
}

// ---------------- CSR build --------------------------------------------------
__global__ __launch_bounds__(256)
void count_kernel(const int* __restrict__ dsts, int* __restrict__ deg) {
  int e = blockIdx.x * blockDim.x + threadIdx.x;
  if (e >= TOTE) return;
  int dst = (e < EE) ? dsts[e] : (e - EE);
  atomicAdd(&deg[dst], 1);
}

__global__ void scan_kernel(const int* __restrict__ deg, int* __restrict__ rowptr) {
  __shared__ int sh[1024];
  int tid = threadIdx.x;
  int base = 0;
  if (tid == 0) rowptr[0] = 0;
  for (int start = 0; start < NN; start += 1024) {
    int i = start + tid;
    int v = (i < NN) ? deg[i] : 0;
    sh[tid] = v;
    __syncthreads();
    for (int off = 1; off < 1024; off <<= 1) {
      int t = (tid >= off) ? sh[tid - off] : 0;
      __syncthreads();
      sh[tid] += t;
      __syncthreads();
    }
    if (i < NN) rowptr[i + 1] = base + sh[tid];
    base += sh[1023];
    __syncthreads();
  }
}

__global__ __launch_bounds__(256)
void scatter_kernel(const int* __restrict__ srcs, const int* __restrict__ dsts,
                    const int* __restrict__ rowptr, int* __restrict__ cursor,
                    int* __restrict__ esrc) {
  int e = blockIdx.x * blockDim.x + threadIdx.x;
  if (e >= TOTE) return;
  int src, dst;
  if (e < EE) { src = srcs[e]; dst = dsts[e]; }
  else        { src = e - EE;  dst = e - EE; }
  int pos = rowptr[dst] + atomicAdd(&cursor[dst], 1);
  esrc[pos] = src;
}

// ---------------- softmax stats: one thread per (node, head) -----------------
template <int H>
__global__ __launch_bounds__(256)
void stats_kernel(const float* __restrict__ AS, const float* __restrict__ AD,
                  const int* __restrict__ rowptr, const int* __restrict__ esrc,
                  float* __restrict__ M, float* __restrict__ DEN) {
  int idx = blockIdx.x * blockDim.x + threadIdx.x;
  if (idx >= NN * H) return;
  int n = idx / H, h = idx % H;
  float ad = AD[idx];
  int s0 = rowptr[n], s1 = rowptr[n + 1];
  float m = -1e30f;
  for (int j = s0; j < s1; ++j) {
    float x = AS[esrc[j] * H + h] + ad;
    float e = x > 0.f ? x : 0.2f * x;
    m = fmaxf(m, e);
  }
  float den = 0.f;
  for (int j = s0; j < s1; ++j) {
    float x = AS[esrc[j] * H + h] + ad;
    float e = x > 0.f ? x : 0.2f * x;
    den += expf(e - m);
  }
  M[idx] = m;
  DEN[idx] = den;
}

// ---------------- aggregation layer 1: one wave per (node, head) -------------
__global__ __launch_bounds__(256)
void agg1_kernel(const float* __restrict__ H1, const float* __restrict__ AS,
                 const float* __restrict__ AD, const float* __restrict__ M,
                 const float* __restrict__ DEN, const int* __restrict__ rowptr,
                 const int* __restrict__ esrc, const float* __restrict__ b1,
                 float* __restrict__ OUT) {
  int gw = (blockIdx.x * blockDim.x + threadIdx.x) >> 6;
  int lane = threadIdx.x & 63;
  if (gw >= NN * HEADS) return;
  int n = gw / HEADS, h = gw % HEADS;
  float ad = AD[gw], m = M[gw];
  float den = DEN[gw] + 1e-16f;
  int s0 = rowptr[n], s1 = rowptr[n + 1];
  float acc = 0.f;
  for (int j = s0; j < s1; ++j) {
    int src = esrc[j];
    float x = AS[src * HEADS + h] + ad;
    float e = x > 0.f ? x : 0.2f * x;
    float w = expf(e - m);
    acc += w * H1[(size_t)src * F1 + h * 64 + lane];
  }
  acc = acc / den + b1[h * 64 + lane];
  // ELU
  OUT[(size_t)n * F1 + h * 64 + lane] = acc > 0.f ? acc : expm1f(acc);
}

// ---------------- aggregation layer 2: one wave per node ---------------------
__global__ __launch_bounds__(256)
void agg2_kernel(const float* __restrict__ H2, const float* __restrict__ AS,
                 const float* __restrict__ AD, const float* __restrict__ M,
                 const float* __restrict__ DEN, const int* __restrict__ rowptr,
                 const int* __restrict__ esrc, const float* __restrict__ b2,
                 float* __restrict__ OUT) {
  int n = (blockIdx.x * blockDim.x + threadIdx.x) >> 6;
  int lane = threadIdx.x & 63;
  if (n >= NN) return;
  float ad = AD[n], m = M[n];
  float den = DEN[n] + 1e-16f;
  int s0 = rowptr[n], s1 = rowptr[n + 1];
  float acc = 0.f;
  for (int j = s0; j < s1; ++j) {
    int src = esrc[j];
    float x = AS[src] + ad;
    float e = x > 0.f ? x : 0.2f * x;
    float w = expf(e - m);
    acc += w * H2[(size_t)src * OUTC + lane];
  }
  OUT[(size_t)n * OUTC + lane] = acc / den + b2[lane];
}

extern "C" void kernel_launch(void* const* d_in, const int* in_sizes, int n_in,
                              void* d_out, int out_size, void* d_ws, size_t ws_size,
                              hipStream_t stream) {
  const float* x      = (const float*)d_in[0];
  const int*   edges  = (const int*)d_in[1];   // [2, EE] int32
  const float* W1     = (const float*)d_in[2];
  const float* a_src1 = (const float*)d_in[3];
  const float* a_dst1 = (const float*)d_in[4];
  const float* b1     = (const float*)d_in[5];
  const float* W2     = (const float*)d_in[6];
  const float* a_src2 = (const float*)d_in[7];
  const float* a_dst2 = (const float*)d_in[8];
  const float* b2     = (const float*)d_in[9];
  float* out = (float*)d_out;

  const int* srcs = edges;
  const int* dsts = edges + EE;

  // ---- workspace layout (floats then ints) ----
  float* H1   = (float*)d_ws;            // NN*F1
  float* AGG1 = H1   + (size_t)NN * F1;  // NN*F1  (layer-2 input after ELU)
  float* H2   = AGG1 + (size_t)NN * F1;  // NN*OUTC
  float* AS1  = H2   + (size_t)NN * OUTC; // NN*HEADS
  float* AD1  = AS1  + (size_t)NN * HEADS;
  float* M1   = AD1  + (size_t)NN * HEADS;
  float* DEN1 = M1   + (size_t)NN * HEADS;
  float* AS2  = DEN1 + (size_t)NN * HEADS; // NN
  float* AD2  = AS2  + NN;
  float* M2   = AD2  + NN;
  float* DEN2 = M2   + NN;
  int* deg    = (int*)(DEN2 + NN);       // NN
  int* rowptr = deg + NN;                // NN+1
  int* cursor = rowptr + NN + 1;         // NN
  int* esrc   = cursor + NN;             // TOTE

  // zero deg/rowptr/cursor region in one shot
  hipMemsetAsync(deg, 0, (size_t)(3 * NN + 1) * sizeof(int), stream);

  // ---- layer 1 GEMM: H1 = x @ W1 ----
  {
    dim3 grid((NN + 63) / 64, F1 / 64);
    gemm64x64<<<grid, 256, 0, stream>>>(x, W1, H1, NN, INC, F1);
  }
  // alpha coefficients
  alpha1_kernel<<<(NN + 3) / 4, 256, 0, stream>>>(H1, a_src1, a_dst1, AS1, AD1);

  // ---- CSR build ----
  count_kernel<<<(TOTE + 255) / 256, 256, 0, stream>>>(dsts, deg);
  scan_kernel<<<1, 1024, 0, stream>>>(deg, rowptr);
  scatter_kernel<<<(TOTE + 255) / 256, 256, 0, stream>>>(srcs, dsts, rowptr, cursor, esrc);

  // ---- layer 1 softmax stats + aggregation (+bias +ELU) ----
  stats_kernel<HEADS><<<(NN * HEADS + 255) / 256, 256, 0, stream>>>(AS1, AD1, rowptr, esrc, M1, DEN1);
  agg1_kernel<<<(NN * HEADS + 3) / 4, 256, 0, stream>>>(H1, AS1, AD1, M1, DEN1, rowptr, esrc, b1, AGG1);

  // ---- layer 2 GEMM: H2 = AGG1 @ W2 ----
  {
    dim3 grid((NN + 63) / 64, OUTC / 64);
    gemm64x64<<<grid, 256, 0, stream>>>(AGG1, W2, H2, NN, F1, OUTC);
  }
  alpha2_kernel<<<(NN + 3) / 4, 256, 0, stream>>>(H2, a_src2, a_dst2, AS2, AD2);
  stats_kernel<1><<<(NN + 255) / 256, 256, 0, stream>>>(AS2, AD2, rowptr, esrc, M2, DEN2);
  agg2_kernel<<<(NN + 3) / 4, 256, 0, stream>>>(H2, AS2, AD2, M2, DEN2, rowptr, esrc, b2, out);
}

// Round 2
// 1002.327 us; speedup vs baseline: 1.2657x; 1.2657x over previous
//
#include <hip/hip_runtime.h>
#include <cstddef>

#define NN   50000
#define EE   800000
#define TOTE 850000      // EE + NN self loops
#define INC  256
#define HEADS 8
#define HID  64
#define F1   512         // HEADS*HID
#define OUTC 64

// ---------------- GEMM: C[M,Nn] = A[M,K] @ B[K,Nn], f32, 64x64 tile ----------
__global__ __launch_bounds__(256)
void gemm64x64(const float* __restrict__ A, const float* __restrict__ B,
               float* __restrict__ C, int M, int K, int Nn) {
  __shared__ float As[64][17];
  __shared__ float Bs[16][68];
  const int tid = threadIdx.x;
  const int tx  = tid & 15;
  const int ty  = tid >> 4;
  const int rowBase = blockIdx.x * 64;
  const int colBase = blockIdx.y * 64;
  const int ar = tid >> 2, ac = (tid & 3) * 4;
  const int br = tid >> 4, bc = (tid & 15) * 4;
  float acc[4][4] = {};
  for (int kt = 0; kt < K; kt += 16) {
    float4 av = make_float4(0.f, 0.f, 0.f, 0.f);
    int grow = rowBase + ar;
    if (grow < M)
      av = *reinterpret_cast<const float4*>(A + (size_t)grow * K + kt + ac);
    As[ar][ac+0] = av.x; As[ar][ac+1] = av.y; As[ar][ac+2] = av.z; As[ar][ac+3] = av.w;
    float4 bv = *reinterpret_cast<const float4*>(B + (size_t)(kt + br) * Nn + colBase + bc);
    Bs[br][bc+0] = bv.x; Bs[br][bc+1] = bv.y; Bs[br][bc+2] = bv.z; Bs[br][bc+3] = bv.w;
    __syncthreads();
    #pragma unroll
    for (int k = 0; k < 16; ++k) {
      float a0 = As[ty][k], a1 = As[ty+16][k], a2 = As[ty+32][k], a3 = As[ty+48][k];
      float b0 = Bs[k][tx], b1 = Bs[k][tx+16], b2 = Bs[k][tx+32], b3 = Bs[k][tx+48];
      acc[0][0] += a0*b0; acc[0][1] += a0*b1; acc[0][2] += a0*b2; acc[0][3] += a0*b3;
      acc[1][0] += a1*b0; acc[1][1] += a1*b1; acc[1][2] += a1*b2; acc[1][3] += a1*b3;
      acc[2][0] += a2*b0; acc[2][1] += a2*b1; acc[2][2] += a2*b2; acc[2][3] += a2*b3;
      acc[3][0] += a3*b0; acc[3][1] += a3*b1; acc[3][2] += a3*b2; acc[3][3] += a3*b3;
    }
    __syncthreads();
  }
  #pragma unroll
  for (int i = 0; i < 4; ++i) {
    int r = rowBase + ty + 16 * i;
    if (r < M) {
      #pragma unroll
      for (int j = 0; j < 4; ++j)
        C[(size_t)r * Nn + colBase + tx + 16 * j] = acc[i][j];
    }
  }
}

// ---------------- alpha coefficients (layer 1): per node, 8 heads ------------
__global__ __launch_bounds__(256)
void alpha1_kernel(const float* __restrict__ H1, const float* __restrict__ a_src,
                   const float* __restrict__ a_dst,
                   float* __restrict__ AS, float* __restrict__ AD) {
  int wave = (blockIdx.x * blockDim.x + threadIdx.x) >> 6;
  int lane = threadIdx.x & 63;
  if (wave >= NN) return;
  const float* hp = H1 + (size_t)wave * F1;
  #pragma unroll
  for (int h = 0; h < HEADS; ++h) {
    float v = hp[h * 64 + lane];
    float s = v * a_src[h * 64 + lane];
    float d = v * a_dst[h * 64 + lane];
    #pragma unroll
    for (int off = 32; off > 0; off >>= 1) {
      s += __shfl_down(s, off);
      d += __shfl_down(d, off);
    }
    if (lane == 0) { AS[wave * HEADS + h] = s; AD[wave * HEADS + h] = d; }
  }
}

// ---------------- alpha coefficients (layer 2): per node, 1 head -------------
__global__ __launch_bounds__(256)
void alpha2_kernel(const float* __restrict__ H2, const float* __restrict__ a_src,
                   const float* __restrict__ a_dst,
                   float* __restrict__ AS, float* __restrict__ AD) {
  int wave = (blockIdx.x * blockDim.x + threadIdx.x) >> 6;
  int lane = threadIdx.x & 63;
  if (wave >= NN) return;
  float v = H2[(size_t)wave * OUTC + lane];
  float s = v * a_src[lane];
  float d = v * a_dst[lane];
  #pragma unroll
  for (int off = 32; off > 0; off >>= 1) {
    s += __shfl_down(s, off);
    d += __shfl_down(d, off);
  }
  if (lane == 0) { AS[wave] = s; AD[wave] = d; }
}

// ---------------- CSR build --------------------------------------------------
__global__ __launch_bounds__(256)
void count_kernel(const int* __restrict__ dsts, int* __restrict__ deg) {
  int e = blockIdx.x * blockDim.x + threadIdx.x;
  if (e >= TOTE) return;
  int dst = (e < EE) ? dsts[e] : (e - EE);
  atomicAdd(&deg[dst], 1);
}

__global__ void scan_kernel(const int* __restrict__ deg, int* __restrict__ rowptr) {
  __shared__ int sh[1024];
  int tid = threadIdx.x;
  int base = 0;
  if (tid == 0) rowptr[0] = 0;
  for (int start = 0; start < NN; start += 1024) {
    int i = start + tid;
    int v = (i < NN) ? deg[i] : 0;
    sh[tid] = v;
    __syncthreads();
    for (int off = 1; off < 1024; off <<= 1) {
      int t = (tid >= off) ? sh[tid - off] : 0;
      __syncthreads();
      sh[tid] += t;
      __syncthreads();
    }
    if (i < NN) rowptr[i + 1] = base + sh[tid];
    base += sh[1023];
    __syncthreads();
  }
}

__global__ __launch_bounds__(256)
void scatter_kernel(const int* __restrict__ srcs, const int* __restrict__ dsts,
                    const int* __restrict__ rowptr, int* __restrict__ cursor,
                    int* __restrict__ esrc) {
  int e = blockIdx.x * blockDim.x + threadIdx.x;
  if (e >= TOTE) return;
  int src, dst;
  if (e < EE) { src = srcs[e]; dst = dsts[e]; }
  else        { src = e - EE;  dst = e - EE; }
  int pos = rowptr[dst] + atomicAdd(&cursor[dst], 1);
  esrc[pos] = src;
}

// ------- softmax stats + normalized edge weights: 1 thread per (node,head) ---
template <int H>
__global__ __launch_bounds__(256)
void stats_alpha_kernel(const float* __restrict__ AS, const float* __restrict__ AD,
                        const int* __restrict__ rowptr, const int* __restrict__ esrc,
                        float* __restrict__ ALPHA) {
  int idx = blockIdx.x * blockDim.x + threadIdx.x;
  if (idx >= NN * H) return;
  int n = idx / H, h = idx % H;
  float ad = AD[idx];
  int s0 = rowptr[n], s1 = rowptr[n + 1];
  float m = -1e30f;
  for (int j = s0; j < s1; ++j) {
    float x = AS[esrc[j] * H + h] + ad;
    float e = x > 0.f ? x : 0.2f * x;
    m = fmaxf(m, e);
  }
  float den = 0.f;
  for (int j = s0; j < s1; ++j) {
    float x = AS[esrc[j] * H + h] + ad;
    float e = x > 0.f ? x : 0.2f * x;
    float ex = expf(e - m);
    ALPHA[j * H + h] = ex;
    den += ex;
  }
  float rden = 1.f / (den + 1e-16f);
  for (int j = s0; j < s1; ++j)
    ALPHA[j * H + h] *= rden;
}

// ------- aggregation layer 1: one wave per (node, head-pair), float2 loads ---
__global__ __launch_bounds__(256)
void agg1_kernel(const float* __restrict__ H1, const float* __restrict__ ALPHA,
                 const int* __restrict__ rowptr, const int* __restrict__ esrc,
                 const float* __restrict__ b1, float* __restrict__ OUT) {
  int gw = (blockIdx.x * blockDim.x + threadIdx.x) >> 6;   // wave id over NN*4
  int lane = threadIdx.x & 63;
  if (gw >= NN * 4) return;
  int n = gw >> 2, hp = gw & 3;
  int off = hp * 128 + lane * 2;        // float offset within 512-float row
  int aidx = hp * 2 + (lane >> 5);      // which head's alpha this lane needs
  int s0 = rowptr[n], s1 = rowptr[n + 1];
  float accx = 0.f, accy = 0.f;
  for (int j = s0; j < s1; ++j) {
    int src = esrc[j];
    float al = ALPHA[j * HEADS + aidx];
    const float2 v = *reinterpret_cast<const float2*>(H1 + (size_t)src * F1 + off);
    accx = fmaf(al, v.x, accx);
    accy = fmaf(al, v.y, accy);
  }
  accx += b1[off];
  accy += b1[off + 1];
  float2 r;
  r.x = accx > 0.f ? accx : expm1f(accx);
  r.y = accy > 0.f ? accy : expm1f(accy);
  *reinterpret_cast<float2*>(OUT + (size_t)n * F1 + off) = r;
}

// ---------------- aggregation layer 2: one wave per node ---------------------
__global__ __launch_bounds__(256)
void agg2_kernel(const float* __restrict__ H2, const float* __restrict__ ALPHA,
                 const int* __restrict__ rowptr, const int* __restrict__ esrc,
                 const float* __restrict__ b2, float* __restrict__ OUT) {
  int n = (blockIdx.x * blockDim.x + threadIdx.x) >> 6;
  int lane = threadIdx.x & 63;
  if (n >= NN) return;
  int s0 = rowptr[n], s1 = rowptr[n + 1];
  float acc = 0.f;
  for (int j = s0; j < s1; ++j) {
    int src = esrc[j];
    float al = ALPHA[j];
    acc = fmaf(al, H2[(size_t)src * OUTC + lane], acc);
  }
  OUT[(size_t)n * OUTC + lane] = acc + b2[lane];
}

extern "C" void kernel_launch(void* const* d_in, const int* in_sizes, int n_in,
                              void* d_out, int out_size, void* d_ws, size_t ws_size,
                              hipStream_t stream) {
  const float* x      = (const float*)d_in[0];
  const int*   edges  = (const int*)d_in[1];   // [2, EE] int32
  const float* W1     = (const float*)d_in[2];
  const float* a_src1 = (const float*)d_in[3];
  const float* a_dst1 = (const float*)d_in[4];
  const float* b1     = (const float*)d_in[5];
  const float* W2     = (const float*)d_in[6];
  const float* a_src2 = (const float*)d_in[7];
  const float* a_dst2 = (const float*)d_in[8];
  const float* b2     = (const float*)d_in[9];
  float* out = (float*)d_out;

  const int* srcs = edges;
  const int* dsts = edges + EE;

  // ---- workspace layout ----
  float* H1     = (float*)d_ws;              // NN*F1
  float* AGG1   = H1     + (size_t)NN * F1;  // NN*F1
  float* H2     = AGG1   + (size_t)NN * F1;  // NN*OUTC
  float* AS1    = H2     + (size_t)NN * OUTC;
  float* AD1    = AS1    + (size_t)NN * HEADS;
  float* AS2    = AD1    + (size_t)NN * HEADS;
  float* AD2    = AS2    + NN;
  float* ALPHA1 = AD2    + NN;               // TOTE*HEADS
  float* ALPHA2 = ALPHA1 + (size_t)TOTE * HEADS;  // TOTE
  int* deg    = (int*)(ALPHA2 + TOTE);       // NN
  int* rowptr = deg + NN;                    // NN+1
  int* cursor = rowptr + NN + 1;             // NN
  int* esrc   = cursor + NN;                 // TOTE

  hipMemsetAsync(deg, 0, (size_t)(3 * NN + 1) * sizeof(int), stream);

  // ---- layer 1 GEMM: H1 = x @ W1 ----
  {
    dim3 grid((NN + 63) / 64, F1 / 64);
    gemm64x64<<<grid, 256, 0, stream>>>(x, W1, H1, NN, INC, F1);
  }
  alpha1_kernel<<<(NN + 3) / 4, 256, 0, stream>>>(H1, a_src1, a_dst1, AS1, AD1);

  // ---- CSR build ----
  count_kernel<<<(TOTE + 255) / 256, 256, 0, stream>>>(dsts, deg);
  scan_kernel<<<1, 1024, 0, stream>>>(deg, rowptr);
  scatter_kernel<<<(TOTE + 255) / 256, 256, 0, stream>>>(srcs, dsts, rowptr, cursor, esrc);

  // ---- layer 1: softmax -> normalized alphas -> aggregation (+bias +ELU) ----
  stats_alpha_kernel<HEADS><<<(NN * HEADS + 255) / 256, 256, 0, stream>>>(AS1, AD1, rowptr, esrc, ALPHA1);
  agg1_kernel<<<(NN * 4 * 64 + 255) / 256, 256, 0, stream>>>(H1, ALPHA1, rowptr, esrc, b1, AGG1);

  // ---- layer 2 GEMM: H2 = AGG1 @ W2 ----
  {
    dim3 grid((NN + 63) / 64, OUTC / 64);
    gemm64x64<<<grid, 256, 0, stream>>>(AGG1, W2, H2, NN, F1, OUTC);
  }
  alpha2_kernel<<<(NN + 3) / 4, 256, 0, stream>>>(H2, a_src2, a_dst2, AS2, AD2);
  stats_alpha_kernel<1><<<(NN + 255) / 256, 256, 0, stream>>>(AS2, AD2, rowptr, esrc, ALPHA2);
  agg2_kernel<<<(NN * 64 + 255) / 256, 256, 0, stream>>>(H2, ALPHA2, rowptr, esrc, b2, out);
}

// Round 3
// 702.241 us; speedup vs baseline: 1.8065x; 1.4273x over previous
//
#include <hip/hip_runtime.h>
#include <cstddef>

#define NN   50000
#define EE   800000
#define TOTE 850000      // EE + NN self loops
#define INC  256
#define HEADS 8
#define F1   512         // HEADS*64
#define OUTC 64
#define NB   ((NN + 255) / 256)   // scan blocks = 196

typedef unsigned short ushort_t;
typedef unsigned int uint_t;

__device__ __forceinline__ ushort_t f32_to_bf16_rne(float f) {
  uint_t u = __float_as_uint(f);
  u += 0x7fffu + ((u >> 16) & 1u);
  return (ushort_t)(u >> 16);
}
__device__ __forceinline__ float bf16lo_to_f32(uint_t u) {  // low ushort
  return __uint_as_float(u << 16);
}
__device__ __forceinline__ float bf16hi_to_f32(uint_t u) {  // high ushort
  return __uint_as_float(u & 0xffff0000u);
}

// ---- fused GEMM: C = A[M,K] @ B[K,Nn]; one 64-col block == one head.
// Writes bf16 C, plus per-row alpha reductions AS/AD (dot with a_src/a_dst).
__global__ __launch_bounds__(256)
void gemm_fused(const float* __restrict__ A, const float* __restrict__ B,
                const float* __restrict__ a_src, const float* __restrict__ a_dst,
                ushort_t* __restrict__ Cbf, float* __restrict__ AS,
                float* __restrict__ AD, int M, int K, int Nn, int nheads) {
  __shared__ float As[64][17];
  __shared__ float Bs[16][68];
  const int tid = threadIdx.x;
  const int tx  = tid & 15;
  const int ty  = tid >> 4;
  const int rowBase = blockIdx.x * 64;
  const int head = blockIdx.y;
  const int colBase = head * 64;
  const int ar = tid >> 2, ac = (tid & 3) * 4;
  const int br = tid >> 4, bc = (tid & 15) * 4;
  float acc[4][4] = {};
  for (int kt = 0; kt < K; kt += 16) {
    float4 av = make_float4(0.f, 0.f, 0.f, 0.f);
    int grow = rowBase + ar;
    if (grow < M)
      av = *reinterpret_cast<const float4*>(A + (size_t)grow * K + kt + ac);
    As[ar][ac+0] = av.x; As[ar][ac+1] = av.y; As[ar][ac+2] = av.z; As[ar][ac+3] = av.w;
    float4 bv = *reinterpret_cast<const float4*>(B + (size_t)(kt + br) * Nn + colBase + bc);
    Bs[br][bc+0] = bv.x; Bs[br][bc+1] = bv.y; Bs[br][bc+2] = bv.z; Bs[br][bc+3] = bv.w;
    __syncthreads();
    #pragma unroll
    for (int k = 0; k < 16; ++k) {
      float a0 = As[ty][k], a1 = As[ty+16][k], a2 = As[ty+32][k], a3 = As[ty+48][k];
      float b0 = Bs[k][tx], b1 = Bs[k][tx+16], b2 = Bs[k][tx+32], b3 = Bs[k][tx+48];
      acc[0][0] += a0*b0; acc[0][1] += a0*b1; acc[0][2] += a0*b2; acc[0][3] += a0*b3;
      acc[1][0] += a1*b0; acc[1][1] += a1*b1; acc[1][2] += a1*b2; acc[1][3] += a1*b3;
      acc[2][0] += a2*b0; acc[2][1] += a2*b1; acc[2][2] += a2*b2; acc[2][3] += a2*b3;
      acc[3][0] += a3*b0; acc[3][1] += a3*b1; acc[3][2] += a3*b2; acc[3][3] += a3*b3;
    }
    __syncthreads();
  }
  // bf16 store + alpha reduction
  float asr[4], adr[4];
  #pragma unroll
  for (int j = 0; j < 4; ++j) {
    asr[j] = a_src[colBase + tx + 16 * j];
    adr[j] = a_dst[colBase + tx + 16 * j];
  }
  #pragma unroll
  for (int i = 0; i < 4; ++i) {
    int r = rowBase + ty + 16 * i;
    if (r >= M) continue;
    float s = 0.f, d = 0.f;
    #pragma unroll
    for (int j = 0; j < 4; ++j) {
      Cbf[(size_t)r * Nn + colBase + tx + 16 * j] = f32_to_bf16_rne(acc[i][j]);
      s = fmaf(acc[i][j], asr[j], s);
      d = fmaf(acc[i][j], adr[j], d);
    }
    #pragma unroll
    for (int off = 8; off > 0; off >>= 1) {
      s += __shfl_xor(s, off);
      d += __shfl_xor(d, off);
    }
    if (tx == 0) {
      AS[(size_t)r * nheads + head] = s;
      AD[(size_t)r * nheads + head] = d;
    }
  }
}

// ---------------- CSR build --------------------------------------------------
__global__ __launch_bounds__(256)
void count_kernel(const int* __restrict__ dsts, int* __restrict__ deg) {
  int e = blockIdx.x * blockDim.x + threadIdx.x;
  if (e >= TOTE) return;
  int dst = (e < EE) ? dsts[e] : (e - EE);
  atomicAdd(&deg[dst], 1);
}

__global__ __launch_bounds__(256)
void scanA_kernel(const int* __restrict__ deg, int* __restrict__ rowptr,
                  int* __restrict__ psum) {
  __shared__ int sh[256];
  int t = threadIdx.x;
  int i = blockIdx.x * 256 + t;
  int v = (i < NN) ? deg[i] : 0;
  sh[t] = v;
  __syncthreads();
  #pragma unroll
  for (int off = 1; off < 256; off <<= 1) {
    int t2 = (t >= off) ? sh[t - off] : 0;
    __syncthreads();
    sh[t] += t2;
    __syncthreads();
  }
  if (i < NN) rowptr[i + 1] = sh[t];
  if (t == 255) psum[blockIdx.x] = sh[255];
}

__global__ void scanB_kernel(int* __restrict__ psum) {
  __shared__ int sh[256];
  int t = threadIdx.x;
  int v = (t < NB) ? psum[t] : 0;
  sh[t] = v;
  __syncthreads();
  #pragma unroll
  for (int off = 1; off < 256; off <<= 1) {
    int t2 = (t >= off) ? sh[t - off] : 0;
    __syncthreads();
    sh[t] += t2;
    __syncthreads();
  }
  if (t < NB) psum[t] = sh[t] - v;   // exclusive
}

__global__ __launch_bounds__(256)
void scanC_kernel(int* __restrict__ rowptr, const int* __restrict__ psum) {
  int i = blockIdx.x * 256 + threadIdx.x;
  if (i < NN) rowptr[i + 1] += psum[blockIdx.x];
  if (i == 0) rowptr[0] = 0;
}

__global__ __launch_bounds__(256)
void scatter_kernel(const int* __restrict__ srcs, const int* __restrict__ dsts,
                    const int* __restrict__ rowptr, int* __restrict__ cursor,
                    int* __restrict__ esrc) {
  int e = blockIdx.x * blockDim.x + threadIdx.x;
  if (e >= TOTE) return;
  int src, dst;
  if (e < EE) { src = srcs[e]; dst = dsts[e]; }
  else        { src = e - EE;  dst = e - EE; }
  int pos = rowptr[dst] + atomicAdd(&cursor[dst], 1);
  esrc[pos] = src;
}

// ------- softmax stats + normalized edge weights: 1 thread per (node,head) ---
template <int H>
__global__ __launch_bounds__(256)
void stats_alpha_kernel(const float* __restrict__ AS, const float* __restrict__ AD,
                        const int* __restrict__ rowptr, const int* __restrict__ esrc,
                        float* __restrict__ ALPHA) {
  int idx = blockIdx.x * blockDim.x + threadIdx.x;
  if (idx >= NN * H) return;
  int n = idx / H, h = idx % H;
  float ad = AD[idx];
  int s0 = rowptr[n], s1 = rowptr[n + 1];
  float m = -1e30f;
  for (int j = s0; j < s1; ++j) {
    float x = AS[esrc[j] * H + h] + ad;
    float e = x > 0.f ? x : 0.2f * x;
    m = fmaxf(m, e);
  }
  float den = 0.f;
  for (int j = s0; j < s1; ++j) {
    float x = AS[esrc[j] * H + h] + ad;
    float e = x > 0.f ? x : 0.2f * x;
    float ex = expf(e - m);
    ALPHA[j * H + h] = ex;
    den += ex;
  }
  float rden = 1.f / (den + 1e-16f);
  for (int j = s0; j < s1; ++j)
    ALPHA[j * H + h] *= rden;
}

// ------- aggregation layer 1: one wave per node, bf16x8 per lane -------------
__global__ __launch_bounds__(256)
void agg1_kernel(const ushort_t* __restrict__ H1bf, const float* __restrict__ ALPHA,
                 const int* __restrict__ rowptr, const int* __restrict__ esrc,
                 const float* __restrict__ b1, float* __restrict__ OUT) {
  int n = (blockIdx.x * blockDim.x + threadIdx.x) >> 6;
  int lane = threadIdx.x & 63;
  if (n >= NN) return;
  int off = lane * 8;          // channel offset within 512
  int h = lane >> 3;           // head of this lane's 8 channels
  int s0 = rowptr[n], s1 = rowptr[n + 1];
  float a0 = 0.f, a1 = 0.f, a2 = 0.f, a3 = 0.f, a4 = 0.f, a5 = 0.f, a6 = 0.f, a7 = 0.f;
  for (int j = s0; j < s1; ++j) {
    int src = esrc[j];
    float al = ALPHA[j * HEADS + h];
    uint4 v = *reinterpret_cast<const uint4*>(H1bf + (size_t)src * F1 + off);
    a0 = fmaf(al, bf16lo_to_f32(v.x), a0);
    a1 = fmaf(al, bf16hi_to_f32(v.x), a1);
    a2 = fmaf(al, bf16lo_to_f32(v.y), a2);
    a3 = fmaf(al, bf16hi_to_f32(v.y), a3);
    a4 = fmaf(al, bf16lo_to_f32(v.z), a4);
    a5 = fmaf(al, bf16hi_to_f32(v.z), a5);
    a6 = fmaf(al, bf16lo_to_f32(v.w), a6);
    a7 = fmaf(al, bf16hi_to_f32(v.w), a7);
  }
  float4 b_lo = *reinterpret_cast<const float4*>(b1 + off);
  float4 b_hi = *reinterpret_cast<const float4*>(b1 + off + 4);
  float r0 = a0 + b_lo.x, r1 = a1 + b_lo.y, r2 = a2 + b_lo.z, r3 = a3 + b_lo.w;
  float r4 = a4 + b_hi.x, r5 = a5 + b_hi.y, r6 = a6 + b_hi.z, r7 = a7 + b_hi.w;
  float4 o_lo, o_hi;
  o_lo.x = r0 > 0.f ? r0 : expm1f(r0);
  o_lo.y = r1 > 0.f ? r1 : expm1f(r1);
  o_lo.z = r2 > 0.f ? r2 : expm1f(r2);
  o_lo.w = r3 > 0.f ? r3 : expm1f(r3);
  o_hi.x = r4 > 0.f ? r4 : expm1f(r4);
  o_hi.y = r5 > 0.f ? r5 : expm1f(r5);
  o_hi.z = r6 > 0.f ? r6 : expm1f(r6);
  o_hi.w = r7 > 0.f ? r7 : expm1f(r7);
  *reinterpret_cast<float4*>(OUT + (size_t)n * F1 + off) = o_lo;
  *reinterpret_cast<float4*>(OUT + (size_t)n * F1 + off + 4) = o_hi;
}

// ---------------- aggregation layer 2: one wave per node ---------------------
__global__ __launch_bounds__(256)
void agg2_kernel(const ushort_t* __restrict__ H2bf, const float* __restrict__ ALPHA,
                 const int* __restrict__ rowptr, const int* __restrict__ esrc,
                 const float* __restrict__ b2, float* __restrict__ OUT) {
  int n = (blockIdx.x * blockDim.x + threadIdx.x) >> 6;
  int lane = threadIdx.x & 63;
  if (n >= NN) return;
  int s0 = rowptr[n], s1 = rowptr[n + 1];
  float acc = 0.f;
  for (int j = s0; j < s1; ++j) {
    int src = esrc[j];
    float al = ALPHA[j];
    float v = __uint_as_float(((uint_t)H2bf[(size_t)src * OUTC + lane]) << 16);
    acc = fmaf(al, v, acc);
  }
  OUT[(size_t)n * OUTC + lane] = acc + b2[lane];
}

extern "C" void kernel_launch(void* const* d_in, const int* in_sizes, int n_in,
                              void* d_out, int out_size, void* d_ws, size_t ws_size,
                              hipStream_t stream) {
  const float* x      = (const float*)d_in[0];
  const int*   edges  = (const int*)d_in[1];   // [2, EE] int32
  const float* W1     = (const float*)d_in[2];
  const float* a_src1 = (const float*)d_in[3];
  const float* a_dst1 = (const float*)d_in[4];
  const float* b1     = (const float*)d_in[5];
  const float* W2     = (const float*)d_in[6];
  const float* a_src2 = (const float*)d_in[7];
  const float* a_dst2 = (const float*)d_in[8];
  const float* b2     = (const float*)d_in[9];
  float* out = (float*)d_out;

  const int* srcs = edges;
  const int* dsts = edges + EE;

  // ---- workspace layout ----
  float* AGG1   = (float*)d_ws;                   // NN*F1 (layer-2 input, f32)
  float* AS1    = AGG1   + (size_t)NN * F1;       // NN*HEADS
  float* AD1    = AS1    + (size_t)NN * HEADS;
  float* AS2    = AD1    + (size_t)NN * HEADS;    // NN
  float* AD2    = AS2    + NN;
  float* ALPHA1 = AD2    + NN;                    // TOTE*HEADS
  float* ALPHA2 = ALPHA1 + (size_t)TOTE * HEADS;  // TOTE
  ushort_t* H1bf = (ushort_t*)(ALPHA2 + TOTE);    // NN*F1 bf16
  ushort_t* H2bf = H1bf + (size_t)NN * F1;        // NN*OUTC bf16
  int* deg    = (int*)(H2bf + (size_t)NN * OUTC); // NN
  int* rowptr = deg + NN;                         // NN+1
  int* cursor = rowptr + NN + 1;                  // NN
  int* psum   = cursor + NN;                      // NB
  int* esrc   = psum + NB;                        // TOTE

  hipMemsetAsync(deg, 0, (size_t)(3 * NN + 1) * sizeof(int), stream);

  // ---- layer 1 GEMM + bf16 store + alpha reduce ----
  {
    dim3 grid((NN + 63) / 64, F1 / 64);
    gemm_fused<<<grid, 256, 0, stream>>>(x, W1, a_src1, a_dst1, H1bf, AS1, AD1,
                                         NN, INC, F1, HEADS);
  }

  // ---- CSR build ----
  count_kernel<<<(TOTE + 255) / 256, 256, 0, stream>>>(dsts, deg);
  scanA_kernel<<<NB, 256, 0, stream>>>(deg, rowptr, psum);
  scanB_kernel<<<1, 256, 0, stream>>>(psum);
  scanC_kernel<<<NB, 256, 0, stream>>>(rowptr, psum);
  scatter_kernel<<<(TOTE + 255) / 256, 256, 0, stream>>>(srcs, dsts, rowptr, cursor, esrc);

  // ---- layer 1: softmax -> normalized alphas -> aggregation (+bias +ELU) ----
  stats_alpha_kernel<HEADS><<<(NN * HEADS + 255) / 256, 256, 0, stream>>>(AS1, AD1, rowptr, esrc, ALPHA1);
  agg1_kernel<<<(NN * 64 + 255) / 256, 256, 0, stream>>>(H1bf, ALPHA1, rowptr, esrc, b1, AGG1);

  // ---- layer 2 GEMM + bf16 store + alpha reduce ----
  {
    dim3 grid((NN + 63) / 64, 1);
    gemm_fused<<<grid, 256, 0, stream>>>(AGG1, W2, a_src2, a_dst2, H2bf, AS2, AD2,
                                         NN, F1, OUTC, 1);
  }
  stats_alpha_kernel<1><<<(NN + 255) / 256, 256, 0, stream>>>(AS2, AD2, rowptr, esrc, ALPHA2);
  agg2_kernel<<<(NN * 64 + 255) / 256, 256, 0, stream>>>(H2bf, ALPHA2, rowptr, esrc, b2, out);
}

// Round 4
// 606.704 us; speedup vs baseline: 2.0910x; 1.1575x over previous
//
#include <hip/hip_runtime.h>
#include <cstddef>

#define NN   50000
#define EE   800000
#define TOTE 850000      // EE + NN self loops
#define INC  256
#define HEADS 8
#define F1   512         // HEADS*64
#define OUTC 64
#define NB   ((NN + 255) / 256)   // scan blocks = 196

typedef unsigned short ushort_t;
typedef unsigned int uint_t;
typedef __attribute__((ext_vector_type(8))) short short8;
typedef __attribute__((ext_vector_type(4))) float f32x4;

__device__ __forceinline__ ushort_t f32_to_bf16_rne(float f) {
  uint_t u = __float_as_uint(f);
  u += 0x7fffu + ((u >> 16) & 1u);
  return (ushort_t)(u >> 16);
}
__device__ __forceinline__ float bf16lo_to_f32(uint_t u) {
  return __uint_as_float(u << 16);
}
__device__ __forceinline__ float bf16hi_to_f32(uint_t u) {
  return __uint_as_float(u & 0xffff0000u);
}

// ---------------- conversions ------------------------------------------------
__global__ __launch_bounds__(256)
void cvt_x_kernel(const float* __restrict__ in, ushort_t* __restrict__ out, long n) {
  long i = ((long)blockIdx.x * 256 + threadIdx.x) * 8;
  if (i >= n) return;
  float4 v0 = *reinterpret_cast<const float4*>(in + i);
  float4 v1 = *reinterpret_cast<const float4*>(in + i + 4);
  ushort_t p[8] = {f32_to_bf16_rne(v0.x), f32_to_bf16_rne(v0.y),
                   f32_to_bf16_rne(v0.z), f32_to_bf16_rne(v0.w),
                   f32_to_bf16_rne(v1.x), f32_to_bf16_rne(v1.y),
                   f32_to_bf16_rne(v1.z), f32_to_bf16_rne(v1.w)};
  *reinterpret_cast<uint4*>(out + i) = *reinterpret_cast<uint4*>(p);
}

// W [K, Nn] f32 -> WT [Nn, K] bf16
__global__ __launch_bounds__(256)
void cvtT_kernel(const float* __restrict__ in, ushort_t* __restrict__ out,
                 int K, int Nn) {
  int i = blockIdx.x * 256 + threadIdx.x;
  if (i >= K * Nn) return;
  int k = i / Nn, n = i % Nn;
  out[(size_t)n * K + k] = f32_to_bf16_rne(in[i]);
}

// ---- MFMA GEMM: C[M,Nn] = A[M,K] @ B[K,Nn], A bf16 [M,K], BT bf16 [Nn,K].
// BM=128, BN=64, BK=64, 4 waves. One 64-col block = one head.
// Epilogue: bf16 C store + AS/AD = C·a_src, C·a_dst per (row, head).
__global__ __launch_bounds__(256)
void gemm_mfma(const ushort_t* __restrict__ A, const ushort_t* __restrict__ BT,
               const float* __restrict__ a_src, const float* __restrict__ a_dst,
               ushort_t* __restrict__ Cbf, float* __restrict__ AS,
               float* __restrict__ AD, int M, int K, int Nn, int nheads) {
  __shared__ __align__(16) ushort_t sA[128 * 64];  // swizzled rows of 128B
  __shared__ __align__(16) ushort_t sB[64 * 64];
  const int tid = threadIdx.x;
  const int w = tid >> 6, lane = tid & 63;
  const int rowBase = blockIdx.x * 128;
  const int head = blockIdx.y;
  const int colBase = head * 64;

  // staging geometry: granule = 16B (8 bf16); 8 granules per 128B row
  const int rsub = tid >> 3;        // 0..31
  const int slot = tid & 7;         // 0..7
  size_t aOff[4]; int aDst[4];
  #pragma unroll
  for (int p = 0; p < 4; ++p) {
    int row = p * 32 + rsub;                       // 0..127
    int rg = rowBase + row; if (rg > M - 1) rg = M - 1;
    aOff[p] = (size_t)rg * K + slot * 8;
    aDst[p] = row * 128 + ((slot ^ (row & 7)) << 4);
  }
  size_t bOff[2]; int bDst[2];
  #pragma unroll
  for (int p = 0; p < 2; ++p) {
    int col = p * 32 + rsub;                       // 0..63
    bOff[p] = (size_t)(colBase + col) * K + slot * 8;
    bDst[p] = col * 128 + ((slot ^ (col & 7)) << 4);
  }

  f32x4 acc[2][4];
  #pragma unroll
  for (int mf = 0; mf < 2; ++mf)
    #pragma unroll
    for (int cf = 0; cf < 4; ++cf)
      acc[mf][cf] = (f32x4){0.f, 0.f, 0.f, 0.f};

  uint4 ra[4], rb[2];
  #pragma unroll
  for (int p = 0; p < 4; ++p) ra[p] = *reinterpret_cast<const uint4*>(A + aOff[p]);
  #pragma unroll
  for (int p = 0; p < 2; ++p) rb[p] = *reinterpret_cast<const uint4*>(BT + bOff[p]);

  const int nkt = K >> 6;
  for (int kt = 0; kt < nkt; ++kt) {
    __syncthreads();
    #pragma unroll
    for (int p = 0; p < 4; ++p)
      *reinterpret_cast<uint4*>((char*)sA + aDst[p]) = ra[p];
    #pragma unroll
    for (int p = 0; p < 2; ++p)
      *reinterpret_cast<uint4*>((char*)sB + bDst[p]) = rb[p];
    __syncthreads();
    if (kt + 1 < nkt) {
      #pragma unroll
      for (int p = 0; p < 4; ++p)
        ra[p] = *reinterpret_cast<const uint4*>(A + aOff[p] + (kt + 1) * 64);
      #pragma unroll
      for (int p = 0; p < 2; ++p)
        rb[p] = *reinterpret_cast<const uint4*>(BT + bOff[p] + (kt + 1) * 64);
    }
    #pragma unroll
    for (int ks = 0; ks < 2; ++ks) {
      const int sl = ks * 4 + (lane >> 4);
      short8 af[2], bfr[4];
      #pragma unroll
      for (int mf = 0; mf < 2; ++mf) {
        int row = w * 32 + mf * 16 + (lane & 15);
        af[mf] = *reinterpret_cast<short8*>((char*)sA + row * 128 + ((sl ^ (row & 7)) << 4));
      }
      #pragma unroll
      for (int cf = 0; cf < 4; ++cf) {
        int col = cf * 16 + (lane & 15);
        bfr[cf] = *reinterpret_cast<short8*>((char*)sB + col * 128 + ((sl ^ (col & 7)) << 4));
      }
      #pragma unroll
      for (int mf = 0; mf < 2; ++mf)
        #pragma unroll
        for (int cf = 0; cf < 4; ++cf)
          acc[mf][cf] = __builtin_amdgcn_mfma_f32_16x16x32_bf16(af[mf], bfr[cf], acc[mf][cf], 0, 0, 0);
    }
  }

  // epilogue: C/D layout col=lane&15, row=(lane>>4)*4+reg
  const int g = lane >> 4, c = lane & 15;
  float asv[4], adv[4];
  #pragma unroll
  for (int cf = 0; cf < 4; ++cf) {
    asv[cf] = a_src[colBase + cf * 16 + c];
    adv[cf] = a_dst[colBase + cf * 16 + c];
  }
  #pragma unroll
  for (int mf = 0; mf < 2; ++mf) {
    #pragma unroll
    for (int r = 0; r < 4; ++r) {
      int row = rowBase + w * 32 + mf * 16 + g * 4 + r;
      bool ok = row < M;
      float s = 0.f, d = 0.f;
      #pragma unroll
      for (int cf = 0; cf < 4; ++cf) {
        float v = acc[mf][cf][r];
        s = fmaf(v, asv[cf], s);
        d = fmaf(v, adv[cf], d);
        if (ok) Cbf[(size_t)row * Nn + colBase + cf * 16 + c] = f32_to_bf16_rne(v);
      }
      #pragma unroll
      for (int off = 8; off > 0; off >>= 1) {
        s += __shfl_xor(s, off);
        d += __shfl_xor(d, off);
      }
      if (ok && c == 0) {
        AS[(size_t)row * nheads + head] = s;
        AD[(size_t)row * nheads + head] = d;
      }
    }
  }
}

// ---------------- CSR build --------------------------------------------------
__global__ __launch_bounds__(256)
void count_kernel(const int* __restrict__ dsts, int* __restrict__ deg) {
  int e = blockIdx.x * blockDim.x + threadIdx.x;
  if (e >= TOTE) return;
  int dst = (e < EE) ? dsts[e] : (e - EE);
  atomicAdd(&deg[dst], 1);
}

__global__ __launch_bounds__(256)
void scanA_kernel(const int* __restrict__ deg, int* __restrict__ rowptr,
                  int* __restrict__ psum) {
  __shared__ int sh[256];
  int t = threadIdx.x;
  int i = blockIdx.x * 256 + t;
  int v = (i < NN) ? deg[i] : 0;
  sh[t] = v;
  __syncthreads();
  #pragma unroll
  for (int off = 1; off < 256; off <<= 1) {
    int t2 = (t >= off) ? sh[t - off] : 0;
    __syncthreads();
    sh[t] += t2;
    __syncthreads();
  }
  if (i < NN) rowptr[i + 1] = sh[t];
  if (t == 255) psum[blockIdx.x] = sh[255];
}

__global__ void scanB_kernel(int* __restrict__ psum) {
  __shared__ int sh[256];
  int t = threadIdx.x;
  int v = (t < NB) ? psum[t] : 0;
  sh[t] = v;
  __syncthreads();
  #pragma unroll
  for (int off = 1; off < 256; off <<= 1) {
    int t2 = (t >= off) ? sh[t - off] : 0;
    __syncthreads();
    sh[t] += t2;
    __syncthreads();
  }
  if (t < NB) psum[t] = sh[t] - v;   // exclusive
}

__global__ __launch_bounds__(256)
void scanC_kernel(int* __restrict__ rowptr, const int* __restrict__ psum) {
  int i = blockIdx.x * 256 + threadIdx.x;
  if (i < NN) rowptr[i + 1] += psum[blockIdx.x];
  if (i == 0) rowptr[0] = 0;
}

__global__ __launch_bounds__(256)
void scatter_kernel(const int* __restrict__ srcs, const int* __restrict__ dsts,
                    const int* __restrict__ rowptr, int* __restrict__ cursor,
                    int* __restrict__ esrc) {
  int e = blockIdx.x * blockDim.x + threadIdx.x;
  if (e >= TOTE) return;
  int src, dst;
  if (e < EE) { src = srcs[e]; dst = dsts[e]; }
  else        { src = e - EE;  dst = e - EE; }
  int pos = rowptr[dst] + atomicAdd(&cursor[dst], 1);
  esrc[pos] = src;
}

// ------- softmax stats + normalized edge weights: 1 thread per (node,head) ---
template <int H>
__global__ __launch_bounds__(256)
void stats_alpha_kernel(const float* __restrict__ AS, const float* __restrict__ AD,
                        const int* __restrict__ rowptr, const int* __restrict__ esrc,
                        float* __restrict__ ALPHA) {
  int idx = blockIdx.x * blockDim.x + threadIdx.x;
  if (idx >= NN * H) return;
  int n = idx / H, h = idx % H;
  float ad = AD[idx];
  int s0 = rowptr[n], s1 = rowptr[n + 1];
  float m = -1e30f;
  for (int j = s0; j < s1; ++j) {
    float x = AS[esrc[j] * H + h] + ad;
    float e = x > 0.f ? x : 0.2f * x;
    m = fmaxf(m, e);
  }
  float den = 0.f;
  for (int j = s0; j < s1; ++j) {
    float x = AS[esrc[j] * H + h] + ad;
    float e = x > 0.f ? x : 0.2f * x;
    float ex = expf(e - m);
    ALPHA[j * H + h] = ex;
    den += ex;
  }
  float rden = 1.f / (den + 1e-16f);
  for (int j = s0; j < s1; ++j)
    ALPHA[j * H + h] *= rden;
}

// ------- aggregation layer 1: one wave per node, bf16x8 per lane, bf16 out ---
__global__ __launch_bounds__(256)
void agg1_kernel(const ushort_t* __restrict__ H1bf, const float* __restrict__ ALPHA,
                 const int* __restrict__ rowptr, const int* __restrict__ esrc,
                 const float* __restrict__ b1, ushort_t* __restrict__ OUT) {
  int n = (blockIdx.x * blockDim.x + threadIdx.x) >> 6;
  int lane = threadIdx.x & 63;
  if (n >= NN) return;
  int off = lane * 8;
  int h = lane >> 3;
  int s0 = rowptr[n], s1 = rowptr[n + 1];
  float a0 = 0.f, a1 = 0.f, a2 = 0.f, a3 = 0.f, a4 = 0.f, a5 = 0.f, a6 = 0.f, a7 = 0.f;
  for (int j = s0; j < s1; ++j) {
    int src = esrc[j];
    float al = ALPHA[j * HEADS + h];
    uint4 v = *reinterpret_cast<const uint4*>(H1bf + (size_t)src * F1 + off);
    a0 = fmaf(al, bf16lo_to_f32(v.x), a0);
    a1 = fmaf(al, bf16hi_to_f32(v.x), a1);
    a2 = fmaf(al, bf16lo_to_f32(v.y), a2);
    a3 = fmaf(al, bf16hi_to_f32(v.y), a3);
    a4 = fmaf(al, bf16lo_to_f32(v.z), a4);
    a5 = fmaf(al, bf16hi_to_f32(v.z), a5);
    a6 = fmaf(al, bf16lo_to_f32(v.w), a6);
    a7 = fmaf(al, bf16hi_to_f32(v.w), a7);
  }
  float4 b_lo = *reinterpret_cast<const float4*>(b1 + off);
  float4 b_hi = *reinterpret_cast<const float4*>(b1 + off + 4);
  float r[8];
  r[0] = a0 + b_lo.x; r[1] = a1 + b_lo.y; r[2] = a2 + b_lo.z; r[3] = a3 + b_lo.w;
  r[4] = a4 + b_hi.x; r[5] = a5 + b_hi.y; r[6] = a6 + b_hi.z; r[7] = a7 + b_hi.w;
  ushort_t p[8];
  #pragma unroll
  for (int i = 0; i < 8; ++i) {
    float e = r[i] > 0.f ? r[i] : expm1f(r[i]);
    p[i] = f32_to_bf16_rne(e);
  }
  *reinterpret_cast<uint4*>(OUT + (size_t)n * F1 + off) = *reinterpret_cast<uint4*>(p);
}

// ---------------- aggregation layer 2: one wave per node ---------------------
__global__ __launch_bounds__(256)
void agg2_kernel(const ushort_t* __restrict__ H2bf, const float* __restrict__ ALPHA,
                 const int* __restrict__ rowptr, const int* __restrict__ esrc,
                 const float* __restrict__ b2, float* __restrict__ OUT) {
  int n = (blockIdx.x * blockDim.x + threadIdx.x) >> 6;
  int lane = threadIdx.x & 63;
  if (n >= NN) return;
  int s0 = rowptr[n], s1 = rowptr[n + 1];
  float acc = 0.f;
  for (int j = s0; j < s1; ++j) {
    int src = esrc[j];
    float al = ALPHA[j];
    float v = __uint_as_float(((uint_t)H2bf[(size_t)src * OUTC + lane]) << 16);
    acc = fmaf(al, v, acc);
  }
  OUT[(size_t)n * OUTC + lane] = acc + b2[lane];
}

extern "C" void kernel_launch(void* const* d_in, const int* in_sizes, int n_in,
                              void* d_out, int out_size, void* d_ws, size_t ws_size,
                              hipStream_t stream) {
  const float* x      = (const float*)d_in[0];
  const int*   edges  = (const int*)d_in[1];   // [2, EE] int32
  const float* W1     = (const float*)d_in[2];
  const float* a_src1 = (const float*)d_in[3];
  const float* a_dst1 = (const float*)d_in[4];
  const float* b1     = (const float*)d_in[5];
  const float* W2     = (const float*)d_in[6];
  const float* a_src2 = (const float*)d_in[7];
  const float* a_dst2 = (const float*)d_in[8];
  const float* b2     = (const float*)d_in[9];
  float* out = (float*)d_out;

  const int* srcs = edges;
  const int* dsts = edges + EE;

  // ---- workspace layout ----
  float* AS1    = (float*)d_ws;                   // NN*HEADS
  float* AD1    = AS1    + (size_t)NN * HEADS;
  float* AS2    = AD1    + (size_t)NN * HEADS;    // NN
  float* AD2    = AS2    + NN;
  float* ALPHA1 = AD2    + NN;                    // TOTE*HEADS
  float* ALPHA2 = ALPHA1 + (size_t)TOTE * HEADS;  // TOTE
  ushort_t* xbf   = (ushort_t*)(ALPHA2 + TOTE);   // NN*INC
  ushort_t* W1T   = xbf  + (size_t)NN * INC;      // F1*INC
  ushort_t* W2T   = W1T  + (size_t)F1 * INC;      // OUTC*F1
  ushort_t* H1bf  = W2T  + (size_t)OUTC * F1;     // NN*F1
  ushort_t* AG1bf = H1bf + (size_t)NN * F1;       // NN*F1
  ushort_t* H2bf  = AG1bf + (size_t)NN * F1;      // NN*OUTC
  int* deg    = (int*)(H2bf + (size_t)NN * OUTC); // NN
  int* rowptr = deg + NN;                         // NN+1
  int* cursor = rowptr + NN + 1;                  // NN
  int* psum   = cursor + NN;                      // NB
  int* esrc   = psum + NB;                        // TOTE

  hipMemsetAsync(deg, 0, (size_t)(3 * NN + 1) * sizeof(int), stream);

  // ---- conversions ----
  cvt_x_kernel<<<((size_t)NN * INC / 8 + 255) / 256, 256, 0, stream>>>(x, xbf, (long)NN * INC);
  cvtT_kernel<<<(INC * F1 + 255) / 256, 256, 0, stream>>>(W1, W1T, INC, F1);
  cvtT_kernel<<<(F1 * OUTC + 255) / 256, 256, 0, stream>>>(W2, W2T, F1, OUTC);

  // ---- CSR build ----
  count_kernel<<<(TOTE + 255) / 256, 256, 0, stream>>>(dsts, deg);
  scanA_kernel<<<NB, 256, 0, stream>>>(deg, rowptr, psum);
  scanB_kernel<<<1, 256, 0, stream>>>(psum);
  scanC_kernel<<<NB, 256, 0, stream>>>(rowptr, psum);
  scatter_kernel<<<(TOTE + 255) / 256, 256, 0, stream>>>(srcs, dsts, rowptr, cursor, esrc);

  // ---- layer 1 GEMM (MFMA) + bf16 store + alpha reduce ----
  {
    dim3 grid((NN + 127) / 128, F1 / 64);
    gemm_mfma<<<grid, 256, 0, stream>>>(xbf, W1T, a_src1, a_dst1, H1bf, AS1, AD1,
                                        NN, INC, F1, HEADS);
  }
  stats_alpha_kernel<HEADS><<<(NN * HEADS + 255) / 256, 256, 0, stream>>>(AS1, AD1, rowptr, esrc, ALPHA1);
  agg1_kernel<<<(NN * 64 + 255) / 256, 256, 0, stream>>>(H1bf, ALPHA1, rowptr, esrc, b1, AG1bf);

  // ---- layer 2 GEMM (MFMA) + bf16 store + alpha reduce ----
  {
    dim3 grid((NN + 127) / 128, 1);
    gemm_mfma<<<grid, 256, 0, stream>>>(AG1bf, W2T, a_src2, a_dst2, H2bf, AS2, AD2,
                                        NN, F1, OUTC, 1);
  }
  stats_alpha_kernel<1><<<(NN + 255) / 256, 256, 0, stream>>>(AS2, AD2, rowptr, esrc, ALPHA2);
  agg2_kernel<<<(NN * 64 + 255) / 256, 256, 0, stream>>>(H2bf, ALPHA2, rowptr, esrc, b2, out);
}

// Round 5
// 561.312 us; speedup vs baseline: 2.2601x; 1.0809x over previous
//
#include <hip/hip_runtime.h>
#include <cstddef>

#define NN   50000
#define EE   800000
#define TOTE 850000      // EE + NN self loops
#define INC  256
#define HEADS 8
#define F1   512         // HEADS*64
#define OUTC 64
#define NB   ((NN + 255) / 256)   // scan blocks = 196

typedef unsigned short ushort_t;
typedef unsigned int uint_t;
typedef __attribute__((ext_vector_type(8))) short short8;
typedef __attribute__((ext_vector_type(4))) float f32x4;

__device__ __forceinline__ ushort_t f32_to_bf16_rne(float f) {
  uint_t u = __float_as_uint(f);
  u += 0x7fffu + ((u >> 16) & 1u);
  return (ushort_t)(u >> 16);
}
__device__ __forceinline__ float bf16lo_to_f32(uint_t u) {
  return __uint_as_float(u << 16);
}
__device__ __forceinline__ float bf16hi_to_f32(uint_t u) {
  return __uint_as_float(u & 0xffff0000u);
}

// ---------------- conversions ------------------------------------------------
__global__ __launch_bounds__(256)
void cvt_x_kernel(const float* __restrict__ in, ushort_t* __restrict__ out, long n) {
  long i = ((long)blockIdx.x * 256 + threadIdx.x) * 8;
  if (i >= n) return;
  float4 v0 = *reinterpret_cast<const float4*>(in + i);
  float4 v1 = *reinterpret_cast<const float4*>(in + i + 4);
  ushort_t p[8] = {f32_to_bf16_rne(v0.x), f32_to_bf16_rne(v0.y),
                   f32_to_bf16_rne(v0.z), f32_to_bf16_rne(v0.w),
                   f32_to_bf16_rne(v1.x), f32_to_bf16_rne(v1.y),
                   f32_to_bf16_rne(v1.z), f32_to_bf16_rne(v1.w)};
  *reinterpret_cast<uint4*>(out + i) = *reinterpret_cast<uint4*>(p);
}

// W [K, Nn] f32 -> WT [Nn, K] bf16
__global__ __launch_bounds__(256)
void cvtT_kernel(const float* __restrict__ in, ushort_t* __restrict__ out,
                 int K, int Nn) {
  int i = blockIdx.x * 256 + threadIdx.x;
  if (i >= K * Nn) return;
  int k = i / Nn, n = i % Nn;
  out[(size_t)n * K + k] = f32_to_bf16_rne(in[i]);
}

// ---- MFMA GEMM: C[M,Nn] = A[M,K] @ B[K,Nn], A bf16 [M,K], BT bf16 [Nn,K].
// BM=128, BN=64, BK=64, 4 waves. One 64-col block = one head.
// 1D grid, head-inner + XCD chunk swizzle so same-rowTile blocks share L2.
// __launch_bounds__(256,2): 256-VGPR budget -> no scratch spill of staging regs.
__global__ __launch_bounds__(256, 2)
void gemm_mfma(const ushort_t* __restrict__ A, const ushort_t* __restrict__ BT,
               const float* __restrict__ a_src, const float* __restrict__ a_dst,
               ushort_t* __restrict__ Cbf, float* __restrict__ AS,
               float* __restrict__ AD, int M, int K, int Nn, int nheads) {
  __shared__ __align__(16) ushort_t sA[128 * 64];  // swizzled rows of 128B
  __shared__ __align__(16) ushort_t sB[64 * 64];
  const int tid = threadIdx.x;
  const int w = tid >> 6, lane = tid & 63;

  // logical block id: chunked XCD swizzle when grid divisible by 8
  int p = blockIdx.x;
  int nwg = gridDim.x;
  int l = ((nwg & 7) == 0) ? ((p & 7) * (nwg >> 3) + (p >> 3)) : p;
  const int rowBase = (l / nheads) * 128;
  const int head = l % nheads;
  const int colBase = head * 64;

  // staging geometry: granule = 16B (8 bf16); 8 granules per 128B row
  const int rsub = tid >> 3;        // 0..31
  const int slot = tid & 7;         // 0..7
  size_t aOff[4]; int aDst[4];
  #pragma unroll
  for (int q = 0; q < 4; ++q) {
    int row = q * 32 + rsub;                       // 0..127
    int rg = rowBase + row; if (rg > M - 1) rg = M - 1;
    aOff[q] = (size_t)rg * K + slot * 8;
    aDst[q] = row * 128 + ((slot ^ (row & 7)) << 4);
  }
  size_t bOff[2]; int bDst[2];
  #pragma unroll
  for (int q = 0; q < 2; ++q) {
    int col = q * 32 + rsub;                       // 0..63
    bOff[q] = (size_t)(colBase + col) * K + slot * 8;
    bDst[q] = col * 128 + ((slot ^ (col & 7)) << 4);
  }

  f32x4 acc[2][4];
  #pragma unroll
  for (int mf = 0; mf < 2; ++mf)
    #pragma unroll
    for (int cf = 0; cf < 4; ++cf)
      acc[mf][cf] = (f32x4){0.f, 0.f, 0.f, 0.f};

  uint4 ra[4], rb[2];
  #pragma unroll
  for (int q = 0; q < 4; ++q) ra[q] = *reinterpret_cast<const uint4*>(A + aOff[q]);
  #pragma unroll
  for (int q = 0; q < 2; ++q) rb[q] = *reinterpret_cast<const uint4*>(BT + bOff[q]);

  const int nkt = K >> 6;
  for (int kt = 0; kt < nkt; ++kt) {
    __syncthreads();
    #pragma unroll
    for (int q = 0; q < 4; ++q)
      *reinterpret_cast<uint4*>((char*)sA + aDst[q]) = ra[q];
    #pragma unroll
    for (int q = 0; q < 2; ++q)
      *reinterpret_cast<uint4*>((char*)sB + bDst[q]) = rb[q];
    __syncthreads();
    if (kt + 1 < nkt) {
      #pragma unroll
      for (int q = 0; q < 4; ++q)
        ra[q] = *reinterpret_cast<const uint4*>(A + aOff[q] + (kt + 1) * 64);
      #pragma unroll
      for (int q = 0; q < 2; ++q)
        rb[q] = *reinterpret_cast<const uint4*>(BT + bOff[q] + (kt + 1) * 64);
    }
    #pragma unroll
    for (int ks = 0; ks < 2; ++ks) {
      const int sl = ks * 4 + (lane >> 4);
      short8 af[2], bfr[4];
      #pragma unroll
      for (int mf = 0; mf < 2; ++mf) {
        int row = w * 32 + mf * 16 + (lane & 15);
        af[mf] = *reinterpret_cast<short8*>((char*)sA + row * 128 + ((sl ^ (row & 7)) << 4));
      }
      #pragma unroll
      for (int cf = 0; cf < 4; ++cf) {
        int col = cf * 16 + (lane & 15);
        bfr[cf] = *reinterpret_cast<short8*>((char*)sB + col * 128 + ((sl ^ (col & 7)) << 4));
      }
      #pragma unroll
      for (int mf = 0; mf < 2; ++mf)
        #pragma unroll
        for (int cf = 0; cf < 4; ++cf)
          acc[mf][cf] = __builtin_amdgcn_mfma_f32_16x16x32_bf16(af[mf], bfr[cf], acc[mf][cf], 0, 0, 0);
    }
  }

  // epilogue: C/D layout col=lane&15, row=(lane>>4)*4+reg
  const int g = lane >> 4, c = lane & 15;
  float asv[4], adv[4];
  #pragma unroll
  for (int cf = 0; cf < 4; ++cf) {
    asv[cf] = a_src[colBase + cf * 16 + c];
    adv[cf] = a_dst[colBase + cf * 16 + c];
  }
  #pragma unroll
  for (int mf = 0; mf < 2; ++mf) {
    #pragma unroll
    for (int r = 0; r < 4; ++r) {
      int row = rowBase + w * 32 + mf * 16 + g * 4 + r;
      bool ok = row < M;
      float s = 0.f, d = 0.f;
      #pragma unroll
      for (int cf = 0; cf < 4; ++cf) {
        float v = acc[mf][cf][r];
        s = fmaf(v, asv[cf], s);
        d = fmaf(v, adv[cf], d);
        if (ok) Cbf[(size_t)row * Nn + colBase + cf * 16 + c] = f32_to_bf16_rne(v);
      }
      #pragma unroll
      for (int off = 8; off > 0; off >>= 1) {
        s += __shfl_xor(s, off);
        d += __shfl_xor(d, off);
      }
      if (ok && c == 0) {
        AS[(size_t)row * nheads + head] = s;
        AD[(size_t)row * nheads + head] = d;
      }
    }
  }
}

// ---------------- CSR build --------------------------------------------------
__global__ __launch_bounds__(256)
void count_kernel(const int* __restrict__ dsts, int* __restrict__ deg) {
  int e = blockIdx.x * blockDim.x + threadIdx.x;
  if (e >= TOTE) return;
  int dst = (e < EE) ? dsts[e] : (e - EE);
  atomicAdd(&deg[dst], 1);
}

__global__ __launch_bounds__(256)
void scanA_kernel(const int* __restrict__ deg, int* __restrict__ rowptr,
                  int* __restrict__ psum) {
  __shared__ int sh[256];
  int t = threadIdx.x;
  int i = blockIdx.x * 256 + t;
  int v = (i < NN) ? deg[i] : 0;
  sh[t] = v;
  __syncthreads();
  #pragma unroll
  for (int off = 1; off < 256; off <<= 1) {
    int t2 = (t >= off) ? sh[t - off] : 0;
    __syncthreads();
    sh[t] += t2;
    __syncthreads();
  }
  if (i < NN) rowptr[i + 1] = sh[t];
  if (t == 255) psum[blockIdx.x] = sh[255];
}

__global__ void scanB_kernel(int* __restrict__ psum) {
  __shared__ int sh[256];
  int t = threadIdx.x;
  int v = (t < NB) ? psum[t] : 0;
  sh[t] = v;
  __syncthreads();
  #pragma unroll
  for (int off = 1; off < 256; off <<= 1) {
    int t2 = (t >= off) ? sh[t - off] : 0;
    __syncthreads();
    sh[t] += t2;
    __syncthreads();
  }
  if (t < NB) psum[t] = sh[t] - v;   // exclusive
}

__global__ __launch_bounds__(256)
void scanC_kernel(int* __restrict__ rowptr, const int* __restrict__ psum) {
  int i = blockIdx.x * 256 + threadIdx.x;
  if (i < NN) rowptr[i + 1] += psum[blockIdx.x];
  if (i == 0) rowptr[0] = 0;
}

__global__ __launch_bounds__(256)
void scatter_kernel(const int* __restrict__ srcs, const int* __restrict__ dsts,
                    const int* __restrict__ rowptr, int* __restrict__ cursor,
                    int* __restrict__ esrc) {
  int e = blockIdx.x * blockDim.x + threadIdx.x;
  if (e >= TOTE) return;
  int src, dst;
  if (e < EE) { src = srcs[e]; dst = dsts[e]; }
  else        { src = e - EE;  dst = e - EE; }
  int pos = rowptr[dst] + atomicAdd(&cursor[dst], 1);
  esrc[pos] = src;
}

// ------- softmax stats + normalized edge weights: 1 thread per (node,head) ---
template <int H>
__global__ __launch_bounds__(256)
void stats_alpha_kernel(const float* __restrict__ AS, const float* __restrict__ AD,
                        const int* __restrict__ rowptr, const int* __restrict__ esrc,
                        float* __restrict__ ALPHA) {
  int idx = blockIdx.x * blockDim.x + threadIdx.x;
  if (idx >= NN * H) return;
  int n = idx / H, h = idx % H;
  float ad = AD[idx];
  int s0 = rowptr[n], s1 = rowptr[n + 1];
  float m = -1e30f;
  for (int j = s0; j < s1; ++j) {
    float x = AS[esrc[j] * H + h] + ad;
    float e = x > 0.f ? x : 0.2f * x;
    m = fmaxf(m, e);
  }
  float den = 0.f;
  for (int j = s0; j < s1; ++j) {
    float x = AS[esrc[j] * H + h] + ad;
    float e = x > 0.f ? x : 0.2f * x;
    float ex = expf(e - m);
    ALPHA[j * H + h] = ex;
    den += ex;
  }
  float rden = 1.f / (den + 1e-16f);
  for (int j = s0; j < s1; ++j)
    ALPHA[j * H + h] *= rden;
}

// ------- aggregation layer 1: one wave per node, bf16x8 per lane, bf16 out ---
__global__ __launch_bounds__(256)
void agg1_kernel(const ushort_t* __restrict__ H1bf, const float* __restrict__ ALPHA,
                 const int* __restrict__ rowptr, const int* __restrict__ esrc,
                 const float* __restrict__ b1, ushort_t* __restrict__ OUT) {
  int n = (blockIdx.x * blockDim.x + threadIdx.x) >> 6;
  int lane = threadIdx.x & 63;
  if (n >= NN) return;
  int off = lane * 8;
  int h = lane >> 3;
  int s0 = rowptr[n], s1 = rowptr[n + 1];
  float a0 = 0.f, a1 = 0.f, a2 = 0.f, a3 = 0.f, a4 = 0.f, a5 = 0.f, a6 = 0.f, a7 = 0.f;
  for (int j = s0; j < s1; ++j) {
    int src = esrc[j];
    float al = ALPHA[j * HEADS + h];
    uint4 v = *reinterpret_cast<const uint4*>(H1bf + (size_t)src * F1 + off);
    a0 = fmaf(al, bf16lo_to_f32(v.x), a0);
    a1 = fmaf(al, bf16hi_to_f32(v.x), a1);
    a2 = fmaf(al, bf16lo_to_f32(v.y), a2);
    a3 = fmaf(al, bf16hi_to_f32(v.y), a3);
    a4 = fmaf(al, bf16lo_to_f32(v.z), a4);
    a5 = fmaf(al, bf16hi_to_f32(v.z), a5);
    a6 = fmaf(al, bf16lo_to_f32(v.w), a6);
    a7 = fmaf(al, bf16hi_to_f32(v.w), a7);
  }
  float4 b_lo = *reinterpret_cast<const float4*>(b1 + off);
  float4 b_hi = *reinterpret_cast<const float4*>(b1 + off + 4);
  float r[8];
  r[0] = a0 + b_lo.x; r[1] = a1 + b_lo.y; r[2] = a2 + b_lo.z; r[3] = a3 + b_lo.w;
  r[4] = a4 + b_hi.x; r[5] = a5 + b_hi.y; r[6] = a6 + b_hi.z; r[7] = a7 + b_hi.w;
  ushort_t p[8];
  #pragma unroll
  for (int i = 0; i < 8; ++i) {
    float e = r[i] > 0.f ? r[i] : expm1f(r[i]);
    p[i] = f32_to_bf16_rne(e);
  }
  *reinterpret_cast<uint4*>(OUT + (size_t)n * F1 + off) = *reinterpret_cast<uint4*>(p);
}

// ---------------- aggregation layer 2: one wave per node ---------------------
__global__ __launch_bounds__(256)
void agg2_kernel(const ushort_t* __restrict__ H2bf, const float* __restrict__ ALPHA,
                 const int* __restrict__ rowptr, const int* __restrict__ esrc,
                 const float* __restrict__ b2, float* __restrict__ OUT) {
  int n = (blockIdx.x * blockDim.x + threadIdx.x) >> 6;
  int lane = threadIdx.x & 63;
  if (n >= NN) return;
  int s0 = rowptr[n], s1 = rowptr[n + 1];
  float acc = 0.f;
  for (int j = s0; j < s1; ++j) {
    int src = esrc[j];
    float al = ALPHA[j];
    float v = __uint_as_float(((uint_t)H2bf[(size_t)src * OUTC + lane]) << 16);
    acc = fmaf(al, v, acc);
  }
  OUT[(size_t)n * OUTC + lane] = acc + b2[lane];
}

extern "C" void kernel_launch(void* const* d_in, const int* in_sizes, int n_in,
                              void* d_out, int out_size, void* d_ws, size_t ws_size,
                              hipStream_t stream) {
  const float* x      = (const float*)d_in[0];
  const int*   edges  = (const int*)d_in[1];   // [2, EE] int32
  const float* W1     = (const float*)d_in[2];
  const float* a_src1 = (const float*)d_in[3];
  const float* a_dst1 = (const float*)d_in[4];
  const float* b1     = (const float*)d_in[5];
  const float* W2     = (const float*)d_in[6];
  const float* a_src2 = (const float*)d_in[7];
  const float* a_dst2 = (const float*)d_in[8];
  const float* b2     = (const float*)d_in[9];
  float* out = (float*)d_out;

  const int* srcs = edges;
  const int* dsts = edges + EE;

  // ---- workspace layout ----
  float* AS1    = (float*)d_ws;                   // NN*HEADS
  float* AD1    = AS1    + (size_t)NN * HEADS;
  float* AS2    = AD1    + (size_t)NN * HEADS;    // NN
  float* AD2    = AS2    + NN;
  float* ALPHA1 = AD2    + NN;                    // TOTE*HEADS
  float* ALPHA2 = ALPHA1 + (size_t)TOTE * HEADS;  // TOTE
  ushort_t* xbf   = (ushort_t*)(ALPHA2 + TOTE);   // NN*INC
  ushort_t* W1T   = xbf  + (size_t)NN * INC;      // F1*INC
  ushort_t* W2T   = W1T  + (size_t)F1 * INC;      // OUTC*F1
  ushort_t* H1bf  = W2T  + (size_t)OUTC * F1;     // NN*F1
  ushort_t* AG1bf = H1bf + (size_t)NN * F1;       // NN*F1
  ushort_t* H2bf  = AG1bf + (size_t)NN * F1;      // NN*OUTC
  int* deg    = (int*)(H2bf + (size_t)NN * OUTC); // NN
  int* rowptr = deg + NN;                         // NN+1
  int* cursor = rowptr + NN + 1;                  // NN
  int* psum   = cursor + NN;                      // NB
  int* esrc   = psum + NB;                        // TOTE

  hipMemsetAsync(deg, 0, (size_t)(3 * NN + 1) * sizeof(int), stream);

  // ---- conversions ----
  cvt_x_kernel<<<((size_t)NN * INC / 8 + 255) / 256, 256, 0, stream>>>(x, xbf, (long)NN * INC);
  cvtT_kernel<<<(INC * F1 + 255) / 256, 256, 0, stream>>>(W1, W1T, INC, F1);
  cvtT_kernel<<<(F1 * OUTC + 255) / 256, 256, 0, stream>>>(W2, W2T, F1, OUTC);

  // ---- CSR build ----
  count_kernel<<<(TOTE + 255) / 256, 256, 0, stream>>>(dsts, deg);
  scanA_kernel<<<NB, 256, 0, stream>>>(deg, rowptr, psum);
  scanB_kernel<<<1, 256, 0, stream>>>(psum);
  scanC_kernel<<<NB, 256, 0, stream>>>(rowptr, psum);
  scatter_kernel<<<(TOTE + 255) / 256, 256, 0, stream>>>(srcs, dsts, rowptr, cursor, esrc);

  // ---- layer 1 GEMM (MFMA) + bf16 store + alpha reduce ----
  gemm_mfma<<<((NN + 127) / 128) * HEADS, 256, 0, stream>>>(
      xbf, W1T, a_src1, a_dst1, H1bf, AS1, AD1, NN, INC, F1, HEADS);
  stats_alpha_kernel<HEADS><<<(NN * HEADS + 255) / 256, 256, 0, stream>>>(AS1, AD1, rowptr, esrc, ALPHA1);
  agg1_kernel<<<(NN * 64 + 255) / 256, 256, 0, stream>>>(H1bf, ALPHA1, rowptr, esrc, b1, AG1bf);

  // ---- layer 2 GEMM (MFMA) + bf16 store + alpha reduce ----
  gemm_mfma<<<(NN + 127) / 128, 256, 0, stream>>>(
      AG1bf, W2T, a_src2, a_dst2, H2bf, AS2, AD2, NN, F1, OUTC, 1);
  stats_alpha_kernel<1><<<(NN + 255) / 256, 256, 0, stream>>>(AS2, AD2, rowptr, esrc, ALPHA2);
  agg2_kernel<<<(NN * 64 + 255) / 256, 256, 0, stream>>>(H2bf, ALPHA2, rowptr, esrc, b2, out);
}

// Round 6
// 449.065 us; speedup vs baseline: 2.8250x; 1.2500x over previous
//
#include <hip/hip_runtime.h>
#include <cstddef>

#define NN   50000
#define EE   800000
#define TOTE 850000      // EE + NN self loops
#define INC  256
#define HEADS 8
#define F1   512         // HEADS*64
#define OUTC 64
#define NB   ((NN + 255) / 256)   // scan blocks = 196

typedef unsigned short ushort_t;
typedef unsigned int uint_t;
typedef __attribute__((ext_vector_type(8))) short short8;
typedef __attribute__((ext_vector_type(4))) float f32x4;

__device__ __forceinline__ ushort_t f32_to_bf16_rne(float f) {
  uint_t u = __float_as_uint(f);
  u += 0x7fffu + ((u >> 16) & 1u);
  return (ushort_t)(u >> 16);
}
__device__ __forceinline__ float bf16lo_to_f32(uint_t u) {
  return __uint_as_float(u << 16);
}
__device__ __forceinline__ float bf16hi_to_f32(uint_t u) {
  return __uint_as_float(u & 0xffff0000u);
}

// async global->LDS, 16B per lane; LDS dest is wave-uniform base + lane*16
__device__ __forceinline__ void gload16(const ushort_t* g, ushort_t* l) {
  __builtin_amdgcn_global_load_lds(
      (const __attribute__((address_space(1))) void*)g,
      (__attribute__((address_space(3))) void*)l, 16, 0, 0);
}

// ---------------- conversions ------------------------------------------------
__global__ __launch_bounds__(256)
void cvt_x_kernel(const float* __restrict__ in, ushort_t* __restrict__ out, long n) {
  long i = ((long)blockIdx.x * 256 + threadIdx.x) * 8;
  if (i >= n) return;
  float4 v0 = *reinterpret_cast<const float4*>(in + i);
  float4 v1 = *reinterpret_cast<const float4*>(in + i + 4);
  ushort_t p[8] = {f32_to_bf16_rne(v0.x), f32_to_bf16_rne(v0.y),
                   f32_to_bf16_rne(v0.z), f32_to_bf16_rne(v0.w),
                   f32_to_bf16_rne(v1.x), f32_to_bf16_rne(v1.y),
                   f32_to_bf16_rne(v1.z), f32_to_bf16_rne(v1.w)};
  *reinterpret_cast<uint4*>(out + i) = *reinterpret_cast<uint4*>(p);
}

// W [K, Nn] f32 -> WT [Nn, K] bf16
__global__ __launch_bounds__(256)
void cvtT_kernel(const float* __restrict__ in, ushort_t* __restrict__ out,
                 int K, int Nn) {
  int i = blockIdx.x * 256 + threadIdx.x;
  if (i >= K * Nn) return;
  int k = i / Nn, n = i % Nn;
  out[(size_t)n * K + k] = f32_to_bf16_rne(in[i]);
}

// ---- MFMA GEMM: C[M,Nn] = A[M,K] @ B[K,Nn], A bf16 [M,K], BT bf16 [Nn,K].
// BM=128, BN=64, BK=64, 4 waves. One 64-col block = one head.
// global_load_lds staging (no staging VGPRs -> no scratch); LDS layout is
// XOR-swizzled via pre-swizzled GLOBAL source (linear LDS dest, rule #21).
__global__ __launch_bounds__(256, 2)
void gemm_mfma(const ushort_t* __restrict__ A, const ushort_t* __restrict__ BT,
               const float* __restrict__ a_src, const float* __restrict__ a_dst,
               ushort_t* __restrict__ Cbf, float* __restrict__ AS,
               float* __restrict__ AD, int M, int K, int Nn, int nheads) {
  __shared__ __align__(16) ushort_t sA[128 * 64];  // rows of 128B, slot-swizzled
  __shared__ __align__(16) ushort_t sB[64 * 64];
  const int tid = threadIdx.x;
  const int w = tid >> 6, lane = tid & 63;

  // logical block id: chunked XCD swizzle when grid divisible by 8
  int p = blockIdx.x;
  int nwg = gridDim.x;
  int l = ((nwg & 7) == 0) ? ((p & 7) * (nwg >> 3) + (p >> 3)) : p;
  const int rowBase = (l / nheads) * 128;
  const int head = l % nheads;
  const int colBase = head * 64;

  // staging: each wave-load covers 8 rows x 128B = 1KB of LDS.
  // lane -> row r0 + (lane>>3), source slot (lane&7) ^ (lane>>3)  (pre-swizzle)
  const int l8 = lane >> 3;
  const int srcslot = (lane & 7) ^ l8;
  size_t aOff[4]; ushort_t* aLds[4];
  #pragma unroll
  for (int q = 0; q < 4; ++q) {
    int r0 = w * 32 + q * 8;
    int grow = rowBase + r0 + l8; if (grow > M - 1) grow = M - 1;
    aOff[q] = (size_t)grow * K + srcslot * 8;
    aLds[q] = sA + r0 * 64;
  }
  size_t bOff[2]; ushort_t* bLds[2];
  #pragma unroll
  for (int q = 0; q < 2; ++q) {
    int c0 = w * 16 + q * 8;
    bOff[q] = (size_t)(colBase + c0 + l8) * K + srcslot * 8;
    bLds[q] = sB + c0 * 64;
  }

  f32x4 acc[2][4];
  #pragma unroll
  for (int mf = 0; mf < 2; ++mf)
    #pragma unroll
    for (int cf = 0; cf < 4; ++cf)
      acc[mf][cf] = (f32x4){0.f, 0.f, 0.f, 0.f};

  const int nkt = K >> 6;
  for (int kt = 0; kt < nkt; ++kt) {
    __syncthreads();   // previous tile fully consumed before overwrite
    #pragma unroll
    for (int q = 0; q < 4; ++q) gload16(A + aOff[q] + kt * 64, aLds[q]);
    #pragma unroll
    for (int q = 0; q < 2; ++q) gload16(BT + bOff[q] + kt * 64, bLds[q]);
    __syncthreads();   // compiler drains vmcnt before barrier -> LDS ready
    #pragma unroll
    for (int ks = 0; ks < 2; ++ks) {
      const int sl = ks * 4 + (lane >> 4);
      short8 af[2], bfr[4];
      #pragma unroll
      for (int mf = 0; mf < 2; ++mf) {
        int row = w * 32 + mf * 16 + (lane & 15);
        af[mf] = *reinterpret_cast<short8*>((char*)sA + row * 128 + ((sl ^ (row & 7)) << 4));
      }
      #pragma unroll
      for (int cf = 0; cf < 4; ++cf) {
        int col = cf * 16 + (lane & 15);
        bfr[cf] = *reinterpret_cast<short8*>((char*)sB + col * 128 + ((sl ^ (col & 7)) << 4));
      }
      #pragma unroll
      for (int mf = 0; mf < 2; ++mf)
        #pragma unroll
        for (int cf = 0; cf < 4; ++cf)
          acc[mf][cf] = __builtin_amdgcn_mfma_f32_16x16x32_bf16(af[mf], bfr[cf], acc[mf][cf], 0, 0, 0);
    }
  }

  // epilogue: C/D layout col=lane&15, row=(lane>>4)*4+reg
  const int g = lane >> 4, c = lane & 15;
  float asv[4], adv[4];
  #pragma unroll
  for (int cf = 0; cf < 4; ++cf) {
    asv[cf] = a_src[colBase + cf * 16 + c];
    adv[cf] = a_dst[colBase + cf * 16 + c];
  }
  #pragma unroll
  for (int mf = 0; mf < 2; ++mf) {
    #pragma unroll
    for (int r = 0; r < 4; ++r) {
      int row = rowBase + w * 32 + mf * 16 + g * 4 + r;
      bool ok = row < M;
      float s = 0.f, d = 0.f;
      #pragma unroll
      for (int cf = 0; cf < 4; ++cf) {
        float v = acc[mf][cf][r];
        s = fmaf(v, asv[cf], s);
        d = fmaf(v, adv[cf], d);
        if (ok) Cbf[(size_t)row * Nn + colBase + cf * 16 + c] = f32_to_bf16_rne(v);
      }
      #pragma unroll
      for (int off = 8; off > 0; off >>= 1) {
        s += __shfl_xor(s, off);
        d += __shfl_xor(d, off);
      }
      if (ok && c == 0) {
        AS[(size_t)row * nheads + head] = s;
        AD[(size_t)row * nheads + head] = d;
      }
    }
  }
}

// ---------------- CSR build --------------------------------------------------
__global__ __launch_bounds__(256)
void count_kernel(const int* __restrict__ dsts, int* __restrict__ deg) {
  int e = blockIdx.x * blockDim.x + threadIdx.x;
  if (e >= TOTE) return;
  int dst = (e < EE) ? dsts[e] : (e - EE);
  atomicAdd(&deg[dst], 1);
}

__global__ __launch_bounds__(256)
void scanA_kernel(const int* __restrict__ deg, int* __restrict__ rowptr,
                  int* __restrict__ psum) {
  __shared__ int sh[256];
  int t = threadIdx.x;
  int i = blockIdx.x * 256 + t;
  int v = (i < NN) ? deg[i] : 0;
  sh[t] = v;
  __syncthreads();
  #pragma unroll
  for (int off = 1; off < 256; off <<= 1) {
    int t2 = (t >= off) ? sh[t - off] : 0;
    __syncthreads();
    sh[t] += t2;
    __syncthreads();
  }
  if (i < NN) rowptr[i + 1] = sh[t];
  if (t == 255) psum[blockIdx.x] = sh[255];
}

__global__ void scanB_kernel(int* __restrict__ psum) {
  __shared__ int sh[256];
  int t = threadIdx.x;
  int v = (t < NB) ? psum[t] : 0;
  sh[t] = v;
  __syncthreads();
  #pragma unroll
  for (int off = 1; off < 256; off <<= 1) {
    int t2 = (t >= off) ? sh[t - off] : 0;
    __syncthreads();
    sh[t] += t2;
    __syncthreads();
  }
  if (t < NB) psum[t] = sh[t] - v;   // exclusive
}

__global__ __launch_bounds__(256)
void scanC_kernel(int* __restrict__ rowptr, const int* __restrict__ psum) {
  int i = blockIdx.x * 256 + threadIdx.x;
  if (i < NN) rowptr[i + 1] += psum[blockIdx.x];
  if (i == 0) rowptr[0] = 0;
}

__global__ __launch_bounds__(256)
void scatter_kernel(const int* __restrict__ srcs, const int* __restrict__ dsts,
                    const int* __restrict__ rowptr, int* __restrict__ cursor,
                    int* __restrict__ esrc) {
  int e = blockIdx.x * blockDim.x + threadIdx.x;
  if (e >= TOTE) return;
  int src, dst;
  if (e < EE) { src = srcs[e]; dst = dsts[e]; }
  else        { src = e - EE;  dst = e - EE; }
  int pos = rowptr[dst] + atomicAdd(&cursor[dst], 1);
  esrc[pos] = src;
}

// ------- softmax stats + normalized edge weights: 1 thread per (node,head) ---
template <int H>
__global__ __launch_bounds__(256)
void stats_alpha_kernel(const float* __restrict__ AS, const float* __restrict__ AD,
                        const int* __restrict__ rowptr, const int* __restrict__ esrc,
                        float* __restrict__ ALPHA) {
  int idx = blockIdx.x * blockDim.x + threadIdx.x;
  if (idx >= NN * H) return;
  int n = idx / H, h = idx % H;
  float ad = AD[idx];
  int s0 = rowptr[n], s1 = rowptr[n + 1];
  float m = -1e30f;
  for (int j = s0; j < s1; ++j) {
    float x = AS[esrc[j] * H + h] + ad;
    float e = x > 0.f ? x : 0.2f * x;
    m = fmaxf(m, e);
  }
  float den = 0.f;
  for (int j = s0; j < s1; ++j) {
    float x = AS[esrc[j] * H + h] + ad;
    float e = x > 0.f ? x : 0.2f * x;
    float ex = expf(e - m);
    ALPHA[j * H + h] = ex;
    den += ex;
  }
  float rden = 1.f / (den + 1e-16f);
  for (int j = s0; j < s1; ++j)
    ALPHA[j * H + h] *= rden;
}

// ------- aggregation layer 1: one wave per node, bf16x8 per lane, bf16 out ---
__global__ __launch_bounds__(256)
void agg1_kernel(const ushort_t* __restrict__ H1bf, const float* __restrict__ ALPHA,
                 const int* __restrict__ rowptr, const int* __restrict__ esrc,
                 const float* __restrict__ b1, ushort_t* __restrict__ OUT) {
  int n = (blockIdx.x * blockDim.x + threadIdx.x) >> 6;
  int lane = threadIdx.x & 63;
  if (n >= NN) return;
  int off = lane * 8;
  int h = lane >> 3;
  int s0 = rowptr[n], s1 = rowptr[n + 1];
  float a0 = 0.f, a1 = 0.f, a2 = 0.f, a3 = 0.f, a4 = 0.f, a5 = 0.f, a6 = 0.f, a7 = 0.f;
  for (int j = s0; j < s1; ++j) {
    int src = esrc[j];
    float al = ALPHA[j * HEADS + h];
    uint4 v = *reinterpret_cast<const uint4*>(H1bf + (size_t)src * F1 + off);
    a0 = fmaf(al, bf16lo_to_f32(v.x), a0);
    a1 = fmaf(al, bf16hi_to_f32(v.x), a1);
    a2 = fmaf(al, bf16lo_to_f32(v.y), a2);
    a3 = fmaf(al, bf16hi_to_f32(v.y), a3);
    a4 = fmaf(al, bf16lo_to_f32(v.z), a4);
    a5 = fmaf(al, bf16hi_to_f32(v.z), a5);
    a6 = fmaf(al, bf16lo_to_f32(v.w), a6);
    a7 = fmaf(al, bf16hi_to_f32(v.w), a7);
  }
  float4 b_lo = *reinterpret_cast<const float4*>(b1 + off);
  float4 b_hi = *reinterpret_cast<const float4*>(b1 + off + 4);
  float r[8];
  r[0] = a0 + b_lo.x; r[1] = a1 + b_lo.y; r[2] = a2 + b_lo.z; r[3] = a3 + b_lo.w;
  r[4] = a4 + b_hi.x; r[5] = a5 + b_hi.y; r[6] = a6 + b_hi.z; r[7] = a7 + b_hi.w;
  ushort_t p[8];
  #pragma unroll
  for (int i = 0; i < 8; ++i) {
    float e = r[i] > 0.f ? r[i] : expm1f(r[i]);
    p[i] = f32_to_bf16_rne(e);
  }
  *reinterpret_cast<uint4*>(OUT + (size_t)n * F1 + off) = *reinterpret_cast<uint4*>(p);
}

// ---------------- aggregation layer 2: one wave per node ---------------------
__global__ __launch_bounds__(256)
void agg2_kernel(const ushort_t* __restrict__ H2bf, const float* __restrict__ ALPHA,
                 const int* __restrict__ rowptr, const int* __restrict__ esrc,
                 const float* __restrict__ b2, float* __restrict__ OUT) {
  int n = (blockIdx.x * blockDim.x + threadIdx.x) >> 6;
  int lane = threadIdx.x & 63;
  if (n >= NN) return;
  int s0 = rowptr[n], s1 = rowptr[n + 1];
  float acc = 0.f;
  for (int j = s0; j < s1; ++j) {
    int src = esrc[j];
    float al = ALPHA[j];
    float v = __uint_as_float(((uint_t)H2bf[(size_t)src * OUTC + lane]) << 16);
    acc = fmaf(al, v, acc);
  }
  OUT[(size_t)n * OUTC + lane] = acc + b2[lane];
}

extern "C" void kernel_launch(void* const* d_in, const int* in_sizes, int n_in,
                              void* d_out, int out_size, void* d_ws, size_t ws_size,
                              hipStream_t stream) {
  const float* x      = (const float*)d_in[0];
  const int*   edges  = (const int*)d_in[1];   // [2, EE] int32
  const float* W1     = (const float*)d_in[2];
  const float* a_src1 = (const float*)d_in[3];
  const float* a_dst1 = (const float*)d_in[4];
  const float* b1     = (const float*)d_in[5];
  const float* W2     = (const float*)d_in[6];
  const float* a_src2 = (const float*)d_in[7];
  const float* a_dst2 = (const float*)d_in[8];
  const float* b2     = (const float*)d_in[9];
  float* out = (float*)d_out;

  const int* srcs = edges;
  const int* dsts = edges + EE;

  // ---- workspace layout ----
  float* AS1    = (float*)d_ws;                   // NN*HEADS
  float* AD1    = AS1    + (size_t)NN * HEADS;
  float* AS2    = AD1    + (size_t)NN * HEADS;    // NN
  float* AD2    = AS2    + NN;
  float* ALPHA1 = AD2    + NN;                    // TOTE*HEADS
  float* ALPHA2 = ALPHA1 + (size_t)TOTE * HEADS;  // TOTE
  ushort_t* xbf   = (ushort_t*)(ALPHA2 + TOTE);   // NN*INC
  ushort_t* W1T   = xbf  + (size_t)NN * INC;      // F1*INC
  ushort_t* W2T   = W1T  + (size_t)F1 * INC;      // OUTC*F1
  ushort_t* H1bf  = W2T  + (size_t)OUTC * F1;     // NN*F1
  ushort_t* AG1bf = H1bf + (size_t)NN * F1;       // NN*F1
  ushort_t* H2bf  = AG1bf + (size_t)NN * F1;      // NN*OUTC
  int* deg    = (int*)(H2bf + (size_t)NN * OUTC); // NN
  int* rowptr = deg + NN;                         // NN+1
  int* cursor = rowptr + NN + 1;                  // NN
  int* psum   = cursor + NN;                      // NB
  int* esrc   = psum + NB;                        // TOTE

  hipMemsetAsync(deg, 0, (size_t)(3 * NN + 1) * sizeof(int), stream);

  // ---- conversions ----
  cvt_x_kernel<<<((size_t)NN * INC / 8 + 255) / 256, 256, 0, stream>>>(x, xbf, (long)NN * INC);
  cvtT_kernel<<<(INC * F1 + 255) / 256, 256, 0, stream>>>(W1, W1T, INC, F1);
  cvtT_kernel<<<(F1 * OUTC + 255) / 256, 256, 0, stream>>>(W2, W2T, F1, OUTC);

  // ---- CSR build ----
  count_kernel<<<(TOTE + 255) / 256, 256, 0, stream>>>(dsts, deg);
  scanA_kernel<<<NB, 256, 0, stream>>>(deg, rowptr, psum);
  scanB_kernel<<<1, 256, 0, stream>>>(psum);
  scanC_kernel<<<NB, 256, 0, stream>>>(rowptr, psum);
  scatter_kernel<<<(TOTE + 255) / 256, 256, 0, stream>>>(srcs, dsts, rowptr, cursor, esrc);

  // ---- layer 1 GEMM (MFMA) + bf16 store + alpha reduce ----
  gemm_mfma<<<((NN + 127) / 128) * HEADS, 256, 0, stream>>>(
      xbf, W1T, a_src1, a_dst1, H1bf, AS1, AD1, NN, INC, F1, HEADS);
  stats_alpha_kernel<HEADS><<<(NN * HEADS + 255) / 256, 256, 0, stream>>>(AS1, AD1, rowptr, esrc, ALPHA1);
  agg1_kernel<<<(NN * 64 + 255) / 256, 256, 0, stream>>>(H1bf, ALPHA1, rowptr, esrc, b1, AG1bf);

  // ---- layer 2 GEMM (MFMA) + bf16 store + alpha reduce ----
  gemm_mfma<<<(NN + 127) / 128, 256, 0, stream>>>(
      AG1bf, W2T, a_src2, a_dst2, H2bf, AS2, AD2, NN, F1, OUTC, 1);
  stats_alpha_kernel<1><<<(NN + 255) / 256, 256, 0, stream>>>(AS2, AD2, rowptr, esrc, ALPHA2);
  agg2_kernel<<<(NN * 64 + 255) / 256, 256, 0, stream>>>(H2bf, ALPHA2, rowptr, esrc, b2, out);
}

// Round 7
// 314.835 us; speedup vs baseline: 4.0295x; 1.4263x over previous
//
#include <hip/hip_runtime.h>
#include <cstddef>

#define NN   50000
#define EE   800000
#define TOTE 850000      // EE + NN self loops
#define INC  256
#define HEADS 8
#define F1   512         // HEADS*64
#define OUTC 64
#define NB   ((NN + 255) / 256)   // scan blocks = 196

typedef unsigned short ushort_t;
typedef unsigned int uint_t;
typedef __attribute__((ext_vector_type(8))) short short8;
typedef __attribute__((ext_vector_type(4))) float f32x4;

__device__ __forceinline__ ushort_t f32_to_bf16_rne(float f) {
  uint_t u = __float_as_uint(f);
  u += 0x7fffu + ((u >> 16) & 1u);
  return (ushort_t)(u >> 16);
}
__device__ __forceinline__ float bf16lo_to_f32(uint_t u) {
  return __uint_as_float(u << 16);
}
__device__ __forceinline__ float bf16hi_to_f32(uint_t u) {
  return __uint_as_float(u & 0xffff0000u);
}
// leaky_relu(x, 0.2) = max(x, 0.2x)  (valid for slope<1)
__device__ __forceinline__ float lrelu(float x) { return fmaxf(x, 0.2f * x); }

// async global->LDS, 16B per lane; LDS dest is wave-uniform base + lane*16
__device__ __forceinline__ void gload16(const ushort_t* g, ushort_t* l) {
  __builtin_amdgcn_global_load_lds(
      (const __attribute__((address_space(1))) void*)g,
      (__attribute__((address_space(3))) void*)l, 16, 0, 0);
}

// ---------------- conversions ------------------------------------------------
__global__ __launch_bounds__(256)
void cvt_x_kernel(const float* __restrict__ in, ushort_t* __restrict__ out, long n) {
  long i = ((long)blockIdx.x * 256 + threadIdx.x) * 8;
  if (i >= n) return;
  float4 v0 = *reinterpret_cast<const float4*>(in + i);
  float4 v1 = *reinterpret_cast<const float4*>(in + i + 4);
  ushort_t p[8] = {f32_to_bf16_rne(v0.x), f32_to_bf16_rne(v0.y),
                   f32_to_bf16_rne(v0.z), f32_to_bf16_rne(v0.w),
                   f32_to_bf16_rne(v1.x), f32_to_bf16_rne(v1.y),
                   f32_to_bf16_rne(v1.z), f32_to_bf16_rne(v1.w)};
  *reinterpret_cast<uint4*>(out + i) = *reinterpret_cast<uint4*>(p);
}

// W [K, Nn] f32 -> WT [Nn, K] bf16
__global__ __launch_bounds__(256)
void cvtT_kernel(const float* __restrict__ in, ushort_t* __restrict__ out,
                 int K, int Nn) {
  int i = blockIdx.x * 256 + threadIdx.x;
  if (i >= K * Nn) return;
  int k = i / Nn, n = i % Nn;
  out[(size_t)n * K + k] = f32_to_bf16_rne(in[i]);
}

// ---- MFMA GEMM: C[M,Nn] = A[M,K] @ B[K,Nn], A bf16 [M,K], BT bf16 [Nn,K].
// BM=128, BN=64, BK=64, 4 waves. One 64-col block = one head.
__global__ __launch_bounds__(256, 2)
void gemm_mfma(const ushort_t* __restrict__ A, const ushort_t* __restrict__ BT,
               const float* __restrict__ a_src, const float* __restrict__ a_dst,
               ushort_t* __restrict__ Cbf, float* __restrict__ AS,
               float* __restrict__ AD, int M, int K, int Nn, int nheads) {
  __shared__ __align__(16) ushort_t sA[128 * 64];  // rows of 128B, slot-swizzled
  __shared__ __align__(16) ushort_t sB[64 * 64];
  const int tid = threadIdx.x;
  const int w = tid >> 6, lane = tid & 63;

  int p = blockIdx.x;
  int nwg = gridDim.x;
  int l = ((nwg & 7) == 0) ? ((p & 7) * (nwg >> 3) + (p >> 3)) : p;
  const int rowBase = (l / nheads) * 128;
  const int head = l % nheads;
  const int colBase = head * 64;

  const int l8 = lane >> 3;
  const int srcslot = (lane & 7) ^ l8;
  size_t aOff[4]; ushort_t* aLds[4];
  #pragma unroll
  for (int q = 0; q < 4; ++q) {
    int r0 = w * 32 + q * 8;
    int grow = rowBase + r0 + l8; if (grow > M - 1) grow = M - 1;
    aOff[q] = (size_t)grow * K + srcslot * 8;
    aLds[q] = sA + r0 * 64;
  }
  size_t bOff[2]; ushort_t* bLds[2];
  #pragma unroll
  for (int q = 0; q < 2; ++q) {
    int c0 = w * 16 + q * 8;
    bOff[q] = (size_t)(colBase + c0 + l8) * K + srcslot * 8;
    bLds[q] = sB + c0 * 64;
  }

  f32x4 acc[2][4];
  #pragma unroll
  for (int mf = 0; mf < 2; ++mf)
    #pragma unroll
    for (int cf = 0; cf < 4; ++cf)
      acc[mf][cf] = (f32x4){0.f, 0.f, 0.f, 0.f};

  const int nkt = K >> 6;
  for (int kt = 0; kt < nkt; ++kt) {
    __syncthreads();
    #pragma unroll
    for (int q = 0; q < 4; ++q) gload16(A + aOff[q] + kt * 64, aLds[q]);
    #pragma unroll
    for (int q = 0; q < 2; ++q) gload16(BT + bOff[q] + kt * 64, bLds[q]);
    __syncthreads();
    #pragma unroll
    for (int ks = 0; ks < 2; ++ks) {
      const int sl = ks * 4 + (lane >> 4);
      short8 af[2], bfr[4];
      #pragma unroll
      for (int mf = 0; mf < 2; ++mf) {
        int row = w * 32 + mf * 16 + (lane & 15);
        af[mf] = *reinterpret_cast<short8*>((char*)sA + row * 128 + ((sl ^ (row & 7)) << 4));
      }
      #pragma unroll
      for (int cf = 0; cf < 4; ++cf) {
        int col = cf * 16 + (lane & 15);
        bfr[cf] = *reinterpret_cast<short8*>((char*)sB + col * 128 + ((sl ^ (col & 7)) << 4));
      }
      #pragma unroll
      for (int mf = 0; mf < 2; ++mf)
        #pragma unroll
        for (int cf = 0; cf < 4; ++cf)
          acc[mf][cf] = __builtin_amdgcn_mfma_f32_16x16x32_bf16(af[mf], bfr[cf], acc[mf][cf], 0, 0, 0);
    }
  }

  const int g = lane >> 4, c = lane & 15;
  float asv[4], adv[4];
  #pragma unroll
  for (int cf = 0; cf < 4; ++cf) {
    asv[cf] = a_src[colBase + cf * 16 + c];
    adv[cf] = a_dst[colBase + cf * 16 + c];
  }
  #pragma unroll
  for (int mf = 0; mf < 2; ++mf) {
    #pragma unroll
    for (int r = 0; r < 4; ++r) {
      int row = rowBase + w * 32 + mf * 16 + g * 4 + r;
      bool ok = row < M;
      float s = 0.f, d = 0.f;
      #pragma unroll
      for (int cf = 0; cf < 4; ++cf) {
        float v = acc[mf][cf][r];
        s = fmaf(v, asv[cf], s);
        d = fmaf(v, adv[cf], d);
        if (ok) Cbf[(size_t)row * Nn + colBase + cf * 16 + c] = f32_to_bf16_rne(v);
      }
      #pragma unroll
      for (int off = 8; off > 0; off >>= 1) {
        s += __shfl_xor(s, off);
        d += __shfl_xor(d, off);
      }
      if (ok && c == 0) {
        AS[(size_t)row * nheads + head] = s;
        AD[(size_t)row * nheads + head] = d;
      }
    }
  }
}

// ---------------- CSR build --------------------------------------------------
__global__ __launch_bounds__(256)
void count_kernel(const int* __restrict__ dsts, int* __restrict__ deg) {
  int e = blockIdx.x * blockDim.x + threadIdx.x;
  if (e >= TOTE) return;
  int dst = (e < EE) ? dsts[e] : (e - EE);
  atomicAdd(&deg[dst], 1);
}

__global__ __launch_bounds__(256)
void scanA_kernel(const int* __restrict__ deg, int* __restrict__ rowptr,
                  int* __restrict__ psum) {
  __shared__ int sh[256];
  int t = threadIdx.x;
  int i = blockIdx.x * 256 + t;
  int v = (i < NN) ? deg[i] : 0;
  sh[t] = v;
  __syncthreads();
  #pragma unroll
  for (int off = 1; off < 256; off <<= 1) {
    int t2 = (t >= off) ? sh[t - off] : 0;
    __syncthreads();
    sh[t] += t2;
    __syncthreads();
  }
  if (i < NN) rowptr[i + 1] = sh[t];
  if (t == 255) psum[blockIdx.x] = sh[255];
}

__global__ void scanB_kernel(int* __restrict__ psum) {
  __shared__ int sh[256];
  int t = threadIdx.x;
  int v = (t < NB) ? psum[t] : 0;
  sh[t] = v;
  __syncthreads();
  #pragma unroll
  for (int off = 1; off < 256; off <<= 1) {
    int t2 = (t >= off) ? sh[t - off] : 0;
    __syncthreads();
    sh[t] += t2;
    __syncthreads();
  }
  if (t < NB) psum[t] = sh[t] - v;   // exclusive
}

__global__ __launch_bounds__(256)
void scanC_kernel(int* __restrict__ rowptr, const int* __restrict__ psum) {
  int i = blockIdx.x * 256 + threadIdx.x;
  if (i < NN) rowptr[i + 1] += psum[blockIdx.x];
  if (i == 0) rowptr[0] = 0;
}

__global__ __launch_bounds__(256)
void scatter_kernel(const int* __restrict__ srcs, const int* __restrict__ dsts,
                    const int* __restrict__ rowptr, int* __restrict__ cursor,
                    int* __restrict__ esrc) {
  int e = blockIdx.x * blockDim.x + threadIdx.x;
  if (e >= TOTE) return;
  int src, dst;
  if (e < EE) { src = srcs[e]; dst = dsts[e]; }
  else        { src = e - EE;  dst = e - EE; }
  int pos = rowptr[dst] + atomicAdd(&cursor[dst], 1);
  esrc[pos] = src;
}

// ------- agg layer 1, fused softmax (no max-sub): one wave per node ----------
// out[n] = (sum_j exp(lrelu(AS[src_j]+AD[n])) * h[src_j]) / (sum_j exp(...))
__global__ __launch_bounds__(256)
void agg1_kernel(const ushort_t* __restrict__ H1bf, const float* __restrict__ AS,
                 const float* __restrict__ AD, const int* __restrict__ rowptr,
                 const int* __restrict__ esrc, const float* __restrict__ b1,
                 ushort_t* __restrict__ OUT) {
  int n = (blockIdx.x * blockDim.x + threadIdx.x) >> 6;
  int lane = threadIdx.x & 63;
  if (n >= NN) return;
  int off = lane * 8;
  int h = lane >> 3;
  float ad = AD[n * HEADS + h];
  int s0 = rowptr[n], s1 = rowptr[n + 1];
  float den = 0.f;
  float a0 = 0.f, a1 = 0.f, a2 = 0.f, a3 = 0.f, a4 = 0.f, a5 = 0.f, a6 = 0.f, a7 = 0.f;
  int j = s0;
  for (; j + 1 < s1; j += 2) {
    int srcA = esrc[j], srcB = esrc[j + 1];
    float asA = AS[srcA * HEADS + h];
    float asB = AS[srcB * HEADS + h];
    uint4 vA = *reinterpret_cast<const uint4*>(H1bf + (size_t)srcA * F1 + off);
    uint4 vB = *reinterpret_cast<const uint4*>(H1bf + (size_t)srcB * F1 + off);
    float wA = __expf(lrelu(asA + ad));
    float wB = __expf(lrelu(asB + ad));
    den += wA + wB;
    a0 = fmaf(wA, bf16lo_to_f32(vA.x), a0); a0 = fmaf(wB, bf16lo_to_f32(vB.x), a0);
    a1 = fmaf(wA, bf16hi_to_f32(vA.x), a1); a1 = fmaf(wB, bf16hi_to_f32(vB.x), a1);
    a2 = fmaf(wA, bf16lo_to_f32(vA.y), a2); a2 = fmaf(wB, bf16lo_to_f32(vB.y), a2);
    a3 = fmaf(wA, bf16hi_to_f32(vA.y), a3); a3 = fmaf(wB, bf16hi_to_f32(vB.y), a3);
    a4 = fmaf(wA, bf16lo_to_f32(vA.z), a4); a4 = fmaf(wB, bf16lo_to_f32(vB.z), a4);
    a5 = fmaf(wA, bf16hi_to_f32(vA.z), a5); a5 = fmaf(wB, bf16hi_to_f32(vB.z), a5);
    a6 = fmaf(wA, bf16lo_to_f32(vA.w), a6); a6 = fmaf(wB, bf16lo_to_f32(vB.w), a6);
    a7 = fmaf(wA, bf16hi_to_f32(vA.w), a7); a7 = fmaf(wB, bf16hi_to_f32(vB.w), a7);
  }
  if (j < s1) {
    int srcA = esrc[j];
    float asA = AS[srcA * HEADS + h];
    uint4 vA = *reinterpret_cast<const uint4*>(H1bf + (size_t)srcA * F1 + off);
    float wA = __expf(lrelu(asA + ad));
    den += wA;
    a0 = fmaf(wA, bf16lo_to_f32(vA.x), a0);
    a1 = fmaf(wA, bf16hi_to_f32(vA.x), a1);
    a2 = fmaf(wA, bf16lo_to_f32(vA.y), a2);
    a3 = fmaf(wA, bf16hi_to_f32(vA.y), a3);
    a4 = fmaf(wA, bf16lo_to_f32(vA.z), a4);
    a5 = fmaf(wA, bf16hi_to_f32(vA.z), a5);
    a6 = fmaf(wA, bf16lo_to_f32(vA.w), a6);
    a7 = fmaf(wA, bf16hi_to_f32(vA.w), a7);
  }
  float rden = 1.f / (den + 1e-16f);
  float4 b_lo = *reinterpret_cast<const float4*>(b1 + off);
  float4 b_hi = *reinterpret_cast<const float4*>(b1 + off + 4);
  float r[8];
  r[0] = fmaf(a0, rden, b_lo.x); r[1] = fmaf(a1, rden, b_lo.y);
  r[2] = fmaf(a2, rden, b_lo.z); r[3] = fmaf(a3, rden, b_lo.w);
  r[4] = fmaf(a4, rden, b_hi.x); r[5] = fmaf(a5, rden, b_hi.y);
  r[6] = fmaf(a6, rden, b_hi.z); r[7] = fmaf(a7, rden, b_hi.w);
  ushort_t pk[8];
  #pragma unroll
  for (int i = 0; i < 8; ++i) {
    float e = r[i] > 0.f ? r[i] : expm1f(r[i]);
    pk[i] = f32_to_bf16_rne(e);
  }
  *reinterpret_cast<uint4*>(OUT + (size_t)n * F1 + off) = *reinterpret_cast<uint4*>(pk);
}

// ------- agg layer 2, fused softmax: one wave per node, 8 edges in flight ----
// lane = grp*8 + slot: grp (lane>>3) picks edge, slot (lane&7) picks 8 channels.
__global__ __launch_bounds__(256)
void agg2_kernel(const ushort_t* __restrict__ H2bf, const float* __restrict__ AS,
                 const float* __restrict__ AD, const int* __restrict__ rowptr,
                 const int* __restrict__ esrc, const float* __restrict__ b2,
                 float* __restrict__ OUT) {
  int n = (blockIdx.x * blockDim.x + threadIdx.x) >> 6;
  int lane = threadIdx.x & 63;
  if (n >= NN) return;
  int grp = lane >> 3;
  int c8 = (lane & 7) * 8;
  float ad = AD[n];
  int s0 = rowptr[n], s1 = rowptr[n + 1];
  float den = 0.f;
  float a0 = 0.f, a1 = 0.f, a2 = 0.f, a3 = 0.f, a4 = 0.f, a5 = 0.f, a6 = 0.f, a7 = 0.f;
  for (int j0 = s0; j0 < s1; j0 += 8) {
    int j = j0 + grp;
    bool valid = j < s1;
    int src = esrc[valid ? j : s0];
    float as = AS[src];
    uint4 v = *reinterpret_cast<const uint4*>(H2bf + (size_t)src * OUTC + c8);
    float w = valid ? __expf(lrelu(as + ad)) : 0.f;
    den += w;
    a0 = fmaf(w, bf16lo_to_f32(v.x), a0);
    a1 = fmaf(w, bf16hi_to_f32(v.x), a1);
    a2 = fmaf(w, bf16lo_to_f32(v.y), a2);
    a3 = fmaf(w, bf16hi_to_f32(v.y), a3);
    a4 = fmaf(w, bf16lo_to_f32(v.z), a4);
    a5 = fmaf(w, bf16hi_to_f32(v.z), a5);
    a6 = fmaf(w, bf16lo_to_f32(v.w), a6);
    a7 = fmaf(w, bf16hi_to_f32(v.w), a7);
  }
  // combine the 8 edge-groups (xor over lane bits 3..5)
  #pragma unroll
  for (int st = 8; st < 64; st <<= 1) {
    den += __shfl_xor(den, st);
    a0 += __shfl_xor(a0, st); a1 += __shfl_xor(a1, st);
    a2 += __shfl_xor(a2, st); a3 += __shfl_xor(a3, st);
    a4 += __shfl_xor(a4, st); a5 += __shfl_xor(a5, st);
    a6 += __shfl_xor(a6, st); a7 += __shfl_xor(a7, st);
  }
  if (grp == 0) {
    float rden = 1.f / (den + 1e-16f);
    float4 o0, o1;
    o0.x = fmaf(a0, rden, b2[c8 + 0]); o0.y = fmaf(a1, rden, b2[c8 + 1]);
    o0.z = fmaf(a2, rden, b2[c8 + 2]); o0.w = fmaf(a3, rden, b2[c8 + 3]);
    o1.x = fmaf(a4, rden, b2[c8 + 4]); o1.y = fmaf(a5, rden, b2[c8 + 5]);
    o1.z = fmaf(a6, rden, b2[c8 + 6]); o1.w = fmaf(a7, rden, b2[c8 + 7]);
    *reinterpret_cast<float4*>(OUT + (size_t)n * OUTC + c8) = o0;
    *reinterpret_cast<float4*>(OUT + (size_t)n * OUTC + c8 + 4) = o1;
  }
}

extern "C" void kernel_launch(void* const* d_in, const int* in_sizes, int n_in,
                              void* d_out, int out_size, void* d_ws, size_t ws_size,
                              hipStream_t stream) {
  const float* x      = (const float*)d_in[0];
  const int*   edges  = (const int*)d_in[1];   // [2, EE] int32
  const float* W1     = (const float*)d_in[2];
  const float* a_src1 = (const float*)d_in[3];
  const float* a_dst1 = (const float*)d_in[4];
  const float* b1     = (const float*)d_in[5];
  const float* W2     = (const float*)d_in[6];
  const float* a_src2 = (const float*)d_in[7];
  const float* a_dst2 = (const float*)d_in[8];
  const float* b2     = (const float*)d_in[9];
  float* out = (float*)d_out;

  const int* srcs = edges;
  const int* dsts = edges + EE;

  // ---- workspace layout ----
  float* AS1    = (float*)d_ws;                   // NN*HEADS
  float* AD1    = AS1    + (size_t)NN * HEADS;
  float* AS2    = AD1    + (size_t)NN * HEADS;    // NN
  float* AD2    = AS2    + NN;
  ushort_t* xbf   = (ushort_t*)(AD2 + NN);        // NN*INC
  ushort_t* W1T   = xbf  + (size_t)NN * INC;      // F1*INC
  ushort_t* W2T   = W1T  + (size_t)F1 * INC;      // OUTC*F1
  ushort_t* H1bf  = W2T  + (size_t)OUTC * F1;     // NN*F1
  ushort_t* AG1bf = H1bf + (size_t)NN * F1;       // NN*F1
  ushort_t* H2bf  = AG1bf + (size_t)NN * F1;      // NN*OUTC
  int* deg    = (int*)(H2bf + (size_t)NN * OUTC); // NN
  int* rowptr = deg + NN;                         // NN+1
  int* cursor = rowptr + NN + 1;                  // NN
  int* psum   = cursor + NN;                      // NB
  int* esrc   = psum + NB;                        // TOTE

  hipMemsetAsync(deg, 0, (size_t)(3 * NN + 1) * sizeof(int), stream);

  // ---- conversions ----
  cvt_x_kernel<<<((size_t)NN * INC / 8 + 255) / 256, 256, 0, stream>>>(x, xbf, (long)NN * INC);
  cvtT_kernel<<<(INC * F1 + 255) / 256, 256, 0, stream>>>(W1, W1T, INC, F1);
  cvtT_kernel<<<(F1 * OUTC + 255) / 256, 256, 0, stream>>>(W2, W2T, F1, OUTC);

  // ---- CSR build ----
  count_kernel<<<(TOTE + 255) / 256, 256, 0, stream>>>(dsts, deg);
  scanA_kernel<<<NB, 256, 0, stream>>>(deg, rowptr, psum);
  scanB_kernel<<<1, 256, 0, stream>>>(psum);
  scanC_kernel<<<NB, 256, 0, stream>>>(rowptr, psum);
  scatter_kernel<<<(TOTE + 255) / 256, 256, 0, stream>>>(srcs, dsts, rowptr, cursor, esrc);

  // ---- layer 1: GEMM (MFMA, fused alpha reduce) -> fused softmax-agg ----
  gemm_mfma<<<((NN + 127) / 128) * HEADS, 256, 0, stream>>>(
      xbf, W1T, a_src1, a_dst1, H1bf, AS1, AD1, NN, INC, F1, HEADS);
  agg1_kernel<<<(NN * 64 + 255) / 256, 256, 0, stream>>>(H1bf, AS1, AD1, rowptr, esrc, b1, AG1bf);

  // ---- layer 2: GEMM (MFMA) -> fused softmax-agg ----
  gemm_mfma<<<(NN + 127) / 128, 256, 0, stream>>>(
      AG1bf, W2T, a_src2, a_dst2, H2bf, AS2, AD2, NN, F1, OUTC, 1);
  agg2_kernel<<<(NN * 64 + 255) / 256, 256, 0, stream>>>(H2bf, AS2, AD2, rowptr, esrc, b2, out);
}

// Round 8
// 312.133 us; speedup vs baseline: 4.0643x; 1.0087x over previous
//
#include <hip/hip_runtime.h>
#include <cstddef>

#define NN   50000
#define EE   800000
#define TOTE 850000      // EE + NN self loops
#define INC  256
#define HEADS 8
#define F1   512         // HEADS*64
#define OUTC 64
#define NB   ((NN + 255) / 256)   // scan blocks = 196

// prelude partition (blocks)
#define PB_CVTX   ((NN * INC / 8 + 255) / 256)        // 6250
#define PB_CVTW1  ((INC * F1 + 255) / 256)            // 512
#define PB_CVTW2  ((F1 * OUTC + 255) / 256)           // 128
#define PB_COUNT  ((TOTE + 255) / 256)                // 3321

typedef unsigned short ushort_t;
typedef unsigned int uint_t;
typedef __attribute__((ext_vector_type(8))) short short8;
typedef __attribute__((ext_vector_type(4))) float f32x4;

__device__ __forceinline__ ushort_t f32_to_bf16_rne(float f) {
  uint_t u = __float_as_uint(f);
  u += 0x7fffu + ((u >> 16) & 1u);
  return (ushort_t)(u >> 16);
}
__device__ __forceinline__ float bf16lo_to_f32(uint_t u) {
  return __uint_as_float(u << 16);
}
__device__ __forceinline__ float bf16hi_to_f32(uint_t u) {
  return __uint_as_float(u & 0xffff0000u);
}
// leaky_relu(x, 0.2) = max(x, 0.2x)  (valid for slope<1)
__device__ __forceinline__ float lrelu(float x) { return fmaxf(x, 0.2f * x); }

// async global->LDS, 16B per lane; LDS dest is wave-uniform base + lane*16
__device__ __forceinline__ void gload16(const ushort_t* g, ushort_t* l) {
  __builtin_amdgcn_global_load_lds(
      (const __attribute__((address_space(1))) void*)g,
      (__attribute__((address_space(3))) void*)l, 16, 0, 0);
}

// ------- fused prelude: cvt_x | cvtT(W1) | cvtT(W2) | count (independent) ----
__global__ __launch_bounds__(256)
void prelude_kernel(const float* __restrict__ x, ushort_t* __restrict__ xbf,
                    const float* __restrict__ W1, ushort_t* __restrict__ W1T,
                    const float* __restrict__ W2, ushort_t* __restrict__ W2T,
                    const int* __restrict__ dsts, int* __restrict__ deg) {
  int b = blockIdx.x;
  if (b < PB_CVTX) {
    long i = ((long)b * 256 + threadIdx.x) * 8;
    if (i >= (long)NN * INC) return;
    float4 v0 = *reinterpret_cast<const float4*>(x + i);
    float4 v1 = *reinterpret_cast<const float4*>(x + i + 4);
    ushort_t p[8] = {f32_to_bf16_rne(v0.x), f32_to_bf16_rne(v0.y),
                     f32_to_bf16_rne(v0.z), f32_to_bf16_rne(v0.w),
                     f32_to_bf16_rne(v1.x), f32_to_bf16_rne(v1.y),
                     f32_to_bf16_rne(v1.z), f32_to_bf16_rne(v1.w)};
    *reinterpret_cast<uint4*>(xbf + i) = *reinterpret_cast<uint4*>(p);
    return;
  }
  b -= PB_CVTX;
  if (b < PB_CVTW1) {
    int i = b * 256 + threadIdx.x;
    if (i >= INC * F1) return;
    int k = i / F1, n = i % F1;
    W1T[(size_t)n * INC + k] = f32_to_bf16_rne(W1[i]);
    return;
  }
  b -= PB_CVTW1;
  if (b < PB_CVTW2) {
    int i = b * 256 + threadIdx.x;
    if (i >= F1 * OUTC) return;
    int k = i / OUTC, n = i % OUTC;
    W2T[(size_t)n * F1 + k] = f32_to_bf16_rne(W2[i]);
    return;
  }
  b -= PB_CVTW2;
  {
    int e = b * 256 + threadIdx.x;
    if (e >= TOTE) return;
    int dst = (e < EE) ? dsts[e] : (e - EE);
    atomicAdd(&deg[dst], 1);
  }
}

// ---- MFMA GEMM: C[M,Nn] = A[M,K] @ B[K,Nn], A bf16 [M,K], BT bf16 [Nn,K].
// BM=128, BN=64, BK=64, 4 waves. One 64-col block = one head.
__global__ __launch_bounds__(256, 2)
void gemm_mfma(const ushort_t* __restrict__ A, const ushort_t* __restrict__ BT,
               const float* __restrict__ a_src, const float* __restrict__ a_dst,
               ushort_t* __restrict__ Cbf, float* __restrict__ AS,
               float* __restrict__ AD, int M, int K, int Nn, int nheads) {
  __shared__ __align__(16) ushort_t sA[128 * 64];  // rows of 128B, slot-swizzled
  __shared__ __align__(16) ushort_t sB[64 * 64];
  const int tid = threadIdx.x;
  const int w = tid >> 6, lane = tid & 63;

  int p = blockIdx.x;
  int nwg = gridDim.x;
  int l = ((nwg & 7) == 0) ? ((p & 7) * (nwg >> 3) + (p >> 3)) : p;
  const int rowBase = (l / nheads) * 128;
  const int head = l % nheads;
  const int colBase = head * 64;

  const int l8 = lane >> 3;
  const int srcslot = (lane & 7) ^ l8;
  size_t aOff[4]; ushort_t* aLds[4];
  #pragma unroll
  for (int q = 0; q < 4; ++q) {
    int r0 = w * 32 + q * 8;
    int grow = rowBase + r0 + l8; if (grow > M - 1) grow = M - 1;
    aOff[q] = (size_t)grow * K + srcslot * 8;
    aLds[q] = sA + r0 * 64;
  }
  size_t bOff[2]; ushort_t* bLds[2];
  #pragma unroll
  for (int q = 0; q < 2; ++q) {
    int c0 = w * 16 + q * 8;
    bOff[q] = (size_t)(colBase + c0 + l8) * K + srcslot * 8;
    bLds[q] = sB + c0 * 64;
  }

  f32x4 acc[2][4];
  #pragma unroll
  for (int mf = 0; mf < 2; ++mf)
    #pragma unroll
    for (int cf = 0; cf < 4; ++cf)
      acc[mf][cf] = (f32x4){0.f, 0.f, 0.f, 0.f};

  const int nkt = K >> 6;
  for (int kt = 0; kt < nkt; ++kt) {
    __syncthreads();
    #pragma unroll
    for (int q = 0; q < 4; ++q) gload16(A + aOff[q] + kt * 64, aLds[q]);
    #pragma unroll
    for (int q = 0; q < 2; ++q) gload16(BT + bOff[q] + kt * 64, bLds[q]);
    __syncthreads();
    #pragma unroll
    for (int ks = 0; ks < 2; ++ks) {
      const int sl = ks * 4 + (lane >> 4);
      short8 af[2], bfr[4];
      #pragma unroll
      for (int mf = 0; mf < 2; ++mf) {
        int row = w * 32 + mf * 16 + (lane & 15);
        af[mf] = *reinterpret_cast<short8*>((char*)sA + row * 128 + ((sl ^ (row & 7)) << 4));
      }
      #pragma unroll
      for (int cf = 0; cf < 4; ++cf) {
        int col = cf * 16 + (lane & 15);
        bfr[cf] = *reinterpret_cast<short8*>((char*)sB + col * 128 + ((sl ^ (col & 7)) << 4));
      }
      #pragma unroll
      for (int mf = 0; mf < 2; ++mf)
        #pragma unroll
        for (int cf = 0; cf < 4; ++cf)
          acc[mf][cf] = __builtin_amdgcn_mfma_f32_16x16x32_bf16(af[mf], bfr[cf], acc[mf][cf], 0, 0, 0);
    }
  }

  const int g = lane >> 4, c = lane & 15;
  float asv[4], adv[4];
  #pragma unroll
  for (int cf = 0; cf < 4; ++cf) {
    asv[cf] = a_src[colBase + cf * 16 + c];
    adv[cf] = a_dst[colBase + cf * 16 + c];
  }
  #pragma unroll
  for (int mf = 0; mf < 2; ++mf) {
    #pragma unroll
    for (int r = 0; r < 4; ++r) {
      int row = rowBase + w * 32 + mf * 16 + g * 4 + r;
      bool ok = row < M;
      float s = 0.f, d = 0.f;
      #pragma unroll
      for (int cf = 0; cf < 4; ++cf) {
        float v = acc[mf][cf][r];
        s = fmaf(v, asv[cf], s);
        d = fmaf(v, adv[cf], d);
        if (ok) Cbf[(size_t)row * Nn + colBase + cf * 16 + c] = f32_to_bf16_rne(v);
      }
      #pragma unroll
      for (int off = 8; off > 0; off >>= 1) {
        s += __shfl_xor(s, off);
        d += __shfl_xor(d, off);
      }
      if (ok && c == 0) {
        AS[(size_t)row * nheads + head] = s;
        AD[(size_t)row * nheads + head] = d;
      }
    }
  }
}

// ---------------- CSR build --------------------------------------------------
__global__ __launch_bounds__(256)
void scanA_kernel(const int* __restrict__ deg, int* __restrict__ rowptr,
                  int* __restrict__ psum) {
  __shared__ int sh[256];
  int t = threadIdx.x;
  int i = blockIdx.x * 256 + t;
  int v = (i < NN) ? deg[i] : 0;
  sh[t] = v;
  __syncthreads();
  #pragma unroll
  for (int off = 1; off < 256; off <<= 1) {
    int t2 = (t >= off) ? sh[t - off] : 0;
    __syncthreads();
    sh[t] += t2;
    __syncthreads();
  }
  if (i < NN) rowptr[i + 1] = sh[t];
  if (t == 255) psum[blockIdx.x] = sh[255];
}

// per-block: inline scan of psum (196 entries) -> add exclusive prefix
__global__ __launch_bounds__(256)
void scanC_kernel(int* __restrict__ rowptr, const int* __restrict__ psum) {
  __shared__ int sh[256];
  int t = threadIdx.x;
  int v = (t < NB) ? psum[t] : 0;
  sh[t] = v;
  __syncthreads();
  #pragma unroll
  for (int off = 1; off < 256; off <<= 1) {
    int t2 = (t >= off) ? sh[t - off] : 0;
    __syncthreads();
    sh[t] += t2;
    __syncthreads();
  }
  int base = (blockIdx.x > 0) ? sh[blockIdx.x - 1] : 0;   // exclusive prefix
  int i = blockIdx.x * 256 + t;
  if (i < NN) rowptr[i + 1] += base;
  if (i == 0) rowptr[0] = 0;
}

__global__ __launch_bounds__(256)
void scatter_kernel(const int* __restrict__ srcs, const int* __restrict__ dsts,
                    const int* __restrict__ rowptr, int* __restrict__ cursor,
                    int* __restrict__ esrc) {
  int e = blockIdx.x * blockDim.x + threadIdx.x;
  if (e >= TOTE) return;
  int src, dst;
  if (e < EE) { src = srcs[e]; dst = dsts[e]; }
  else        { src = e - EE;  dst = e - EE; }
  int pos = rowptr[dst] + atomicAdd(&cursor[dst], 1);
  esrc[pos] = src;
}

// ------- agg layer 1, fused softmax (no max-sub): one wave per node ----------
// 4-edge unroll: 4 independent gather chains in flight per wave.
__global__ __launch_bounds__(256)
void agg1_kernel(const ushort_t* __restrict__ H1bf, const float* __restrict__ AS,
                 const float* __restrict__ AD, const int* __restrict__ rowptr,
                 const int* __restrict__ esrc, const float* __restrict__ b1,
                 ushort_t* __restrict__ OUT) {
  int n = (blockIdx.x * blockDim.x + threadIdx.x) >> 6;
  int lane = threadIdx.x & 63;
  if (n >= NN) return;
  int off = lane * 8;
  int h = lane >> 3;
  float ad = AD[n * HEADS + h];
  int s0 = rowptr[n], s1 = rowptr[n + 1];
  float den = 0.f;
  float a0 = 0.f, a1 = 0.f, a2 = 0.f, a3 = 0.f, a4 = 0.f, a5 = 0.f, a6 = 0.f, a7 = 0.f;
  int j = s0;
  for (; j + 3 < s1; j += 4) {
    int src[4];
    #pragma unroll
    for (int u = 0; u < 4; ++u) src[u] = esrc[j + u];
    float as[4]; uint4 v[4];
    #pragma unroll
    for (int u = 0; u < 4; ++u) {
      as[u] = AS[src[u] * HEADS + h];
      v[u] = *reinterpret_cast<const uint4*>(H1bf + (size_t)src[u] * F1 + off);
    }
    #pragma unroll
    for (int u = 0; u < 4; ++u) {
      float wgt = __expf(lrelu(as[u] + ad));
      den += wgt;
      a0 = fmaf(wgt, bf16lo_to_f32(v[u].x), a0);
      a1 = fmaf(wgt, bf16hi_to_f32(v[u].x), a1);
      a2 = fmaf(wgt, bf16lo_to_f32(v[u].y), a2);
      a3 = fmaf(wgt, bf16hi_to_f32(v[u].y), a3);
      a4 = fmaf(wgt, bf16lo_to_f32(v[u].z), a4);
      a5 = fmaf(wgt, bf16hi_to_f32(v[u].z), a5);
      a6 = fmaf(wgt, bf16lo_to_f32(v[u].w), a6);
      a7 = fmaf(wgt, bf16hi_to_f32(v[u].w), a7);
    }
  }
  for (; j < s1; ++j) {
    int src = esrc[j];
    float as = AS[src * HEADS + h];
    uint4 v = *reinterpret_cast<const uint4*>(H1bf + (size_t)src * F1 + off);
    float wgt = __expf(lrelu(as + ad));
    den += wgt;
    a0 = fmaf(wgt, bf16lo_to_f32(v.x), a0);
    a1 = fmaf(wgt, bf16hi_to_f32(v.x), a1);
    a2 = fmaf(wgt, bf16lo_to_f32(v.y), a2);
    a3 = fmaf(wgt, bf16hi_to_f32(v.y), a3);
    a4 = fmaf(wgt, bf16lo_to_f32(v.z), a4);
    a5 = fmaf(wgt, bf16hi_to_f32(v.z), a5);
    a6 = fmaf(wgt, bf16lo_to_f32(v.w), a6);
    a7 = fmaf(wgt, bf16hi_to_f32(v.w), a7);
  }
  float rden = 1.f / (den + 1e-16f);
  float4 b_lo = *reinterpret_cast<const float4*>(b1 + off);
  float4 b_hi = *reinterpret_cast<const float4*>(b1 + off + 4);
  float r[8];
  r[0] = fmaf(a0, rden, b_lo.x); r[1] = fmaf(a1, rden, b_lo.y);
  r[2] = fmaf(a2, rden, b_lo.z); r[3] = fmaf(a3, rden, b_lo.w);
  r[4] = fmaf(a4, rden, b_hi.x); r[5] = fmaf(a5, rden, b_hi.y);
  r[6] = fmaf(a6, rden, b_hi.z); r[7] = fmaf(a7, rden, b_hi.w);
  ushort_t pk[8];
  #pragma unroll
  for (int i = 0; i < 8; ++i) {
    float e = r[i] > 0.f ? r[i] : expm1f(r[i]);
    pk[i] = f32_to_bf16_rne(e);
  }
  *reinterpret_cast<uint4*>(OUT + (size_t)n * F1 + off) = *reinterpret_cast<uint4*>(pk);
}

// ------- agg layer 2, fused softmax: one wave per node, 8 edges in flight ----
__global__ __launch_bounds__(256)
void agg2_kernel(const ushort_t* __restrict__ H2bf, const float* __restrict__ AS,
                 const float* __restrict__ AD, const int* __restrict__ rowptr,
                 const int* __restrict__ esrc, const float* __restrict__ b2,
                 float* __restrict__ OUT) {
  int n = (blockIdx.x * blockDim.x + threadIdx.x) >> 6;
  int lane = threadIdx.x & 63;
  if (n >= NN) return;
  int grp = lane >> 3;
  int c8 = (lane & 7) * 8;
  float ad = AD[n];
  int s0 = rowptr[n], s1 = rowptr[n + 1];
  float den = 0.f;
  float a0 = 0.f, a1 = 0.f, a2 = 0.f, a3 = 0.f, a4 = 0.f, a5 = 0.f, a6 = 0.f, a7 = 0.f;
  for (int j0 = s0; j0 < s1; j0 += 8) {
    int j = j0 + grp;
    bool valid = j < s1;
    int src = esrc[valid ? j : s0];
    float as = AS[src];
    uint4 v = *reinterpret_cast<const uint4*>(H2bf + (size_t)src * OUTC + c8);
    float w = valid ? __expf(lrelu(as + ad)) : 0.f;
    den += w;
    a0 = fmaf(w, bf16lo_to_f32(v.x), a0);
    a1 = fmaf(w, bf16hi_to_f32(v.x), a1);
    a2 = fmaf(w, bf16lo_to_f32(v.y), a2);
    a3 = fmaf(w, bf16hi_to_f32(v.y), a3);
    a4 = fmaf(w, bf16lo_to_f32(v.z), a4);
    a5 = fmaf(w, bf16hi_to_f32(v.z), a5);
    a6 = fmaf(w, bf16lo_to_f32(v.w), a6);
    a7 = fmaf(w, bf16hi_to_f32(v.w), a7);
  }
  #pragma unroll
  for (int st = 8; st < 64; st <<= 1) {
    den += __shfl_xor(den, st);
    a0 += __shfl_xor(a0, st); a1 += __shfl_xor(a1, st);
    a2 += __shfl_xor(a2, st); a3 += __shfl_xor(a3, st);
    a4 += __shfl_xor(a4, st); a5 += __shfl_xor(a5, st);
    a6 += __shfl_xor(a6, st); a7 += __shfl_xor(a7, st);
  }
  if (grp == 0) {
    float rden = 1.f / (den + 1e-16f);
    float4 o0, o1;
    o0.x = fmaf(a0, rden, b2[c8 + 0]); o0.y = fmaf(a1, rden, b2[c8 + 1]);
    o0.z = fmaf(a2, rden, b2[c8 + 2]); o0.w = fmaf(a3, rden, b2[c8 + 3]);
    o1.x = fmaf(a4, rden, b2[c8 + 4]); o1.y = fmaf(a5, rden, b2[c8 + 5]);
    o1.z = fmaf(a6, rden, b2[c8 + 6]); o1.w = fmaf(a7, rden, b2[c8 + 7]);
    *reinterpret_cast<float4*>(OUT + (size_t)n * OUTC + c8) = o0;
    *reinterpret_cast<float4*>(OUT + (size_t)n * OUTC + c8 + 4) = o1;
  }
}

extern "C" void kernel_launch(void* const* d_in, const int* in_sizes, int n_in,
                              void* d_out, int out_size, void* d_ws, size_t ws_size,
                              hipStream_t stream) {
  const float* x      = (const float*)d_in[0];
  const int*   edges  = (const int*)d_in[1];   // [2, EE] int32
  const float* W1     = (const float*)d_in[2];
  const float* a_src1 = (const float*)d_in[3];
  const float* a_dst1 = (const float*)d_in[4];
  const float* b1     = (const float*)d_in[5];
  const float* W2     = (const float*)d_in[6];
  const float* a_src2 = (const float*)d_in[7];
  const float* a_dst2 = (const float*)d_in[8];
  const float* b2     = (const float*)d_in[9];
  float* out = (float*)d_out;

  const int* srcs = edges;
  const int* dsts = edges + EE;

  // ---- workspace layout ----
  float* AS1    = (float*)d_ws;                   // NN*HEADS
  float* AD1    = AS1    + (size_t)NN * HEADS;
  float* AS2    = AD1    + (size_t)NN * HEADS;    // NN
  float* AD2    = AS2    + NN;
  ushort_t* xbf   = (ushort_t*)(AD2 + NN);        // NN*INC
  ushort_t* W1T   = xbf  + (size_t)NN * INC;      // F1*INC
  ushort_t* W2T   = W1T  + (size_t)F1 * INC;      // OUTC*F1
  ushort_t* H1bf  = W2T  + (size_t)OUTC * F1;     // NN*F1
  ushort_t* AG1bf = H1bf + (size_t)NN * F1;       // NN*F1
  ushort_t* H2bf  = AG1bf + (size_t)NN * F1;      // NN*OUTC
  int* deg    = (int*)(H2bf + (size_t)NN * OUTC); // NN
  int* rowptr = deg + NN;                         // NN+1
  int* cursor = rowptr + NN + 1;                  // NN
  int* psum   = cursor + NN;                      // NB
  int* esrc   = psum + NB;                        // TOTE

  hipMemsetAsync(deg, 0, (size_t)(3 * NN + 1) * sizeof(int), stream);

  // ---- fused prelude: conversions + degree count ----
  prelude_kernel<<<PB_CVTX + PB_CVTW1 + PB_CVTW2 + PB_COUNT, 256, 0, stream>>>(
      x, xbf, W1, W1T, W2, W2T, dsts, deg);

  // ---- CSR build ----
  scanA_kernel<<<NB, 256, 0, stream>>>(deg, rowptr, psum);
  scanC_kernel<<<NB, 256, 0, stream>>>(rowptr, psum);
  scatter_kernel<<<(TOTE + 255) / 256, 256, 0, stream>>>(srcs, dsts, rowptr, cursor, esrc);

  // ---- layer 1: GEMM (MFMA, fused alpha reduce) -> fused softmax-agg ----
  gemm_mfma<<<((NN + 127) / 128) * HEADS, 256, 0, stream>>>(
      xbf, W1T, a_src1, a_dst1, H1bf, AS1, AD1, NN, INC, F1, HEADS);
  agg1_kernel<<<(NN * 64 + 255) / 256, 256, 0, stream>>>(H1bf, AS1, AD1, rowptr, esrc, b1, AG1bf);

  // ---- layer 2: GEMM (MFMA) -> fused softmax-agg ----
  gemm_mfma<<<(NN + 127) / 128, 256, 0, stream>>>(
      AG1bf, W2T, a_src2, a_dst2, H2bf, AS2, AD2, NN, F1, OUTC, 1);
  agg2_kernel<<<(NN * 64 + 255) / 256, 256, 0, stream>>>(H2bf, AS2, AD2, rowptr, esrc, b2, out);
}